// Round 11
// baseline (315.714 us; speedup 1.0000x reference)
//
#include <hip/hip_runtime.h>
#include <math.h>

#define HID 2048
#define NH 32
#define NKV 8
#define HD 64
#define BB 2
#define SS 2048
#define MTOT (BB * SS) // 4096

typedef __bf16 bf16;
typedef __bf16 bf16x8 __attribute__((ext_vector_type(8)));
typedef __bf16 bf16x4 __attribute__((ext_vector_type(4)));
typedef float f32x4 __attribute__((ext_vector_type(4)));

#define MFMA16(a, b, c) __builtin_amdgcn_mfma_f32_16x16x32_bf16((a), (b), (c), 0, 0, 0)

__device__ __forceinline__ void load_lds16(const void* g, void* l) {
  __builtin_amdgcn_global_load_lds((const __attribute__((address_space(1))) void*)g,
                                   (__attribute__((address_space(3))) void*)l, 16, 0, 0);
}

#define FENCE() asm volatile("" ::: "memory")
// Tile-top sync: counted vmcnt (never 0 in main loop) + lgkmcnt(0) so this
// wave's ds_reads have COMPLETED before it enters the barrier (orders them
// against other waves' post-barrier global_load_lds writebacks), then barrier.
#define SYNC_VM(N) do { FENCE(); \
  asm volatile("s_waitcnt vmcnt(" #N ") lgkmcnt(0)" ::: "memory"); \
  __builtin_amdgcn_s_barrier(); FENCE(); } while (0)

// ---------------- fused fp32 -> bf16 convert (EXACT R0 version - fastest measured) ----------------
// R8/R9/R10 A/B: all cvt variants within ~3 us; this one is the best. Leave alone.
__global__ void cvt_all(const float* __restrict__ hs, const float* __restrict__ Wq,
                        const float* __restrict__ Wk, const float* __restrict__ Wv,
                        const float* __restrict__ Wo,
                        bf16* __restrict__ A_b, bf16* __restrict__ Wq_b,
                        bf16* __restrict__ Wk_b, bf16* __restrict__ Wv_b,
                        bf16* __restrict__ Wo_b) {
  int bid = blockIdx.x;
  const float* src;
  bf16* dst;
  if (bid < 8192)       { src = hs; dst = A_b; }
  else if (bid < 12288) { src = Wq; dst = Wq_b; bid -= 8192; }
  else if (bid < 13312) { src = Wk; dst = Wk_b; bid -= 12288; }
  else if (bid < 14336) { src = Wv; dst = Wv_b; bid -= 13312; }
  else                  { src = Wo; dst = Wo_b; bid -= 14336; }
  int i = (bid * 256 + threadIdx.x) * 4;
  float4 v = *(const float4*)(src + i);
  bf16x4 o;
  o[0] = (bf16)v.x; o[1] = (bf16)v.y; o[2] = (bf16)v.z; o[3] = (bf16)v.w;
  *(bf16x4*)(dst + i) = o;
}

// ---------------- NEW qkv core: 4 waves, per-wave 128x64 output (LDS-BW fix) ----------------
// R10 diagnosis: the BK32 8-wave core is LDS-PORT-bound (~87%: 64 b128 reads
// + 24KB staged writes per 2.1-MFLOP block-step). This core keeps the SAME
// verified sync skeleton (3 rotating 24KB buffers, counted SYNC_VM, inverse
// swizzle staging, conflict-free XOR reads) but gives each wave a 128x64
// output tile (m201's wave shape): 12 fragment reads per 32 MFMA instead of
// 8 per 16 -- 25% less LDS-read traffic per FLOP, and only 4 waves staging
// (half the LDS-write pressure per step spread over the same work).
// BM=256, BN=128, BK=32; 256 threads = 4 waves (2M x 2N); acc[8][4].
// Staging: thread t owns LDS 16B-slots {t, t+256, t+512, t+768} of the 16KB
// A region (rows {r, r+64, r+128, r+192}, r = 2*(t>>3) + (cu>>2)) and slots
// {t, t+256} of the 8KB B region. Slot offsets of 256 shift the pair index
// by 32 (== 0 mod 8) so the swizzle term cu is unchanged across j.
// SYNC_VM(6): 6 loads/thread/step; at step top all but tile kt+1's 6 done.
__device__ __forceinline__ void gemm_core_w4(const char* Agc, const char* Bgc,
                                             char* lds, f32x4 (&acc)[8][4]) {
  constexpr int ABYTES = 16384;     // A tile bytes (256 x 32 bf16)
  constexpr int BUFB = 24576;       // + B tile (128 x 32 bf16)
  constexpr int NT = HID / 32;      // 64 K-tiles

  const int tid = threadIdx.x;      // [0,256)
  const int w = tid >> 6, lane = tid & 63;
  const int l16 = lane & 15, quad = lane >> 4;
  const int wr = w >> 1, wc = w & 1;

  const int cu = (tid & 7) ^ ((tid >> 3) & 7);
  const int srcR0 = 2 * (tid >> 3) + (cu >> 2);   // 0..63
  const int srcC = (cu & 3) * 16;
  const char* gA = Agc + (size_t)srcR0 * (HID * 2) + srcC;
  const char* gB = Bgc + (size_t)srcR0 * (HID * 2) + srcC;
  const int db = tid * 16;          // linear LDS slot base (wave-uniform + lane*16)

  const int acg16 = ((((l16 & 1) << 2) | quad) ^ ((l16 >> 1) & 7)) * 16;
  const int aoff = (wr * 64 + (l16 >> 1)) * 128 + acg16;   // wr*128 rows
  const int boff = ABYTES + (wc * 32 + (l16 >> 1)) * 128 + acg16;  // wc*64 cols

  // prologue: stage K-tiles 0 and 1 (6 loads per thread per tile: 4 A + 2 B)
#pragma unroll
  for (int t0 = 0; t0 < 2; ++t0) {
    char* lb = lds + t0 * BUFB;
#pragma unroll
    for (int j = 0; j < 4; ++j)
      load_lds16(gA + (size_t)j * 64 * (HID * 2) + t0 * 64, lb + db + j * 4096);
#pragma unroll
    for (int j = 0; j < 2; ++j)
      load_lds16(gB + (size_t)j * 64 * (HID * 2) + t0 * 64, lb + ABYTES + db + j * 4096);
  }

  char* cur = lds;
  char* stg = lds + 2 * BUFB;
  for (int kt = 0; kt < NT; ++kt) {
    // all but the newest 6 loads (tile kt+1's) complete -> tile kt resident;
    // lgkmcnt(0)+barrier publishes buf (kt+2)%3 fully-read before overwrite.
    SYNC_VM(6);
    const int ks = (kt + 2 < NT) ? (kt + 2) * 64 : (NT - 1) * 64;

    // issue async stage of tile kt+2 (stays in flight across next barrier)
#pragma unroll
    for (int j = 0; j < 4; ++j)
      load_lds16(gA + (size_t)j * 64 * (HID * 2) + ks, stg + db + j * 4096);
#pragma unroll
    for (int j = 0; j < 2; ++j)
      load_lds16(gB + (size_t)j * 64 * (HID * 2) + ks, stg + ABYTES + db + j * 4096);
    FENCE();  // pin stage-issue before the ds_reads

    bf16x8 af[8], bfr[4];
#pragma unroll
    for (int ni = 0; ni < 4; ++ni)
      bfr[ni] = *(const bf16x8*)(cur + boff + ni * 1024);
#pragma unroll
    for (int mi = 0; mi < 8; ++mi)
      af[mi] = *(const bf16x8*)(cur + aoff + mi * 1024);
    __builtin_amdgcn_s_setprio(1);
#pragma unroll
    for (int mi = 0; mi < 8; ++mi)
#pragma unroll
      for (int ni = 0; ni < 4; ++ni)
        acc[mi][ni] = MFMA16(af[mi], bfr[ni], acc[mi][ni]);
    __builtin_amdgcn_s_setprio(0);

    cur = (cur == lds + 2 * BUFB) ? lds : cur + BUFB;
    stg = (stg == lds + 2 * BUFB) ? lds : stg + BUFB;
  }
  asm volatile("s_waitcnt vmcnt(0)" ::: "memory");
}

// ---------------- BK=64 single-phase core (verified round 6; gemm_out only) ----------------
__device__ __forceinline__ void gemm_core_k64(const char* Agc, const char* Bgc,
                                              char* lds, f32x4 (&acc)[4][4]) {
  constexpr int ABYTES = 32768;   // A tile: 256 rows x 64 cols bf16
  constexpr int BUFB = 49152;     // + B tile: 128 rows x 64 cols bf16
  constexpr int NT = HID / 64;    // 32 K-steps

  const int tid = threadIdx.x;
  const int w = tid >> 6, lane = tid & 63;
  const int l16 = lane & 15, quad = lane >> 4;
  const int wr = w >> 1, wc = w & 1;
  const int wb = w * 1024;        // wave-uniform LDS staging base

  const int cu = (lane & 7) ^ ((lane >> 3) & 7);
  const char* gA = Agc + (size_t)(w * 8 + (lane >> 3)) * 4096 + cu * 16;
  const char* gB = Bgc + (size_t)(w * 8 + (lane >> 3)) * 4096 + cu * 16;

  const int aswz = l16 & 7;
  const int a_k0 = ((0 + quad) ^ aswz) * 16;   // ks = 0
  const int a_k1 = ((4 + quad) ^ aswz) * 16;   // ks = 1
  const int arow = (wr * 64 + l16) * 128;
  const int brow = (wc * 64 + l16) * 128;

#pragma unroll
  for (int t0 = 0; t0 < 2; ++t0) {
    char* lb = lds + t0 * BUFB;
#pragma unroll
    for (int j = 0; j < 4; ++j)
      load_lds16(gA + (size_t)j * (64 * 4096) + t0 * 128, lb + wb + j * 8192);
#pragma unroll
    for (int j = 0; j < 2; ++j)
      load_lds16(gB + (size_t)j * (64 * 4096) + t0 * 128, lb + ABYTES + wb + j * 8192);
  }

  char* cur = lds;
  char* stg = lds + 2 * BUFB;
  for (int kt = 0; kt < NT; ++kt) {
    SYNC_VM(6);
    const int ks = (kt + 2 < NT) ? (kt + 2) : (NT - 1);
    const size_t ko = (size_t)ks * 128;

#pragma unroll
    for (int j = 0; j < 4; ++j)
      load_lds16(gA + (size_t)j * (64 * 4096) + ko, stg + wb + j * 8192);
#pragma unroll
    for (int j = 0; j < 2; ++j)
      load_lds16(gB + (size_t)j * (64 * 4096) + ko, stg + ABYTES + wb + j * 8192);
    FENCE();

    const char* Ac = cur;
    const char* Bc = cur + ABYTES;
    bf16x8 af0[4], af1[4], bf0[4], bf1[4];
#pragma unroll
    for (int ni = 0; ni < 4; ++ni) {
      bf0[ni] = *(const bf16x8*)(Bc + brow + ni * 2048 + a_k0);
      bf1[ni] = *(const bf16x8*)(Bc + brow + ni * 2048 + a_k1);
    }
#pragma unroll
    for (int mi = 0; mi < 4; ++mi) {
      af0[mi] = *(const bf16x8*)(Ac + arow + mi * 2048 + a_k0);
      af1[mi] = *(const bf16x8*)(Ac + arow + mi * 2048 + a_k1);
    }
    __builtin_amdgcn_s_setprio(1);
#pragma unroll
    for (int mi = 0; mi < 4; ++mi)
#pragma unroll
      for (int ni = 0; ni < 4; ++ni) {
        acc[mi][ni] = MFMA16(af0[mi], bf0[ni], acc[mi][ni]);
        acc[mi][ni] = MFMA16(af1[mi], bf1[ni], acc[mi][ni]);
      }
    __builtin_amdgcn_s_setprio(0);

    cur = (cur == lds + 2 * BUFB) ? lds : cur + BUFB;
    stg = (stg == lds + 2 * BUFB) ? lds : stg + BUFB;
  }
  asm volatile("s_waitcnt vmcnt(0)" ::: "memory");
}

// ---------------- fused QKV projection + RoPE epilogue (new w4 core) ----------------
#define QSCALE 0.1803368801f
#define L2B 0.4152410118f  // log2(10000)/32
__global__ __launch_bounds__(256, 2) void gemm_qkv(const bf16* __restrict__ A,
                                                   const bf16* __restrict__ Wq,
                                                   const bf16* __restrict__ Wk,
                                                   const bf16* __restrict__ Wv,
                                                   bf16* __restrict__ Qb,
                                                   bf16* __restrict__ Kb,
                                                   bf16* __restrict__ Vt) {
  __shared__ __align__(16) char lds[3 * 24576];  // 72 KB -> 2 WG/CU (8 waves)
  const int tileM = blockIdx.x * 256;
  const int n0 = blockIdx.y * 128;
  const bf16* Wp;
  int mode;
  if (n0 < HID) { Wp = Wq + (size_t)n0 * HID; mode = 0; }
  else if (n0 < HID + 512) { Wp = Wk + (size_t)(n0 - HID) * HID; mode = 1; }
  else { Wp = Wv + (size_t)(n0 - HID - 512) * HID; mode = 2; }

  f32x4 acc[8][4];
#pragma unroll
  for (int i = 0; i < 8; ++i)
#pragma unroll
    for (int j = 0; j < 4; ++j) acc[i][j] = (f32x4){0.f, 0.f, 0.f, 0.f};

  gemm_core_w4((const char*)(A + (size_t)tileM * HID), (const char*)Wp, lds, acc);

  const int tid = threadIdx.x;
  const int w = tid >> 6, lane = tid & 63;
  const int l16 = lane & 15, quad = lane >> 4;
  const int wr = w >> 1, wc = w & 1;
  const int mbase = tileM + wr * 128;
  const int cb = n0 + wc * 64;  // 64-aligned -> wave col span = one head

  if (mode == 2) {
    // V: transposed layout [b,kvh,d,s]
#pragma unroll
    for (int mi = 0; mi < 8; ++mi)
#pragma unroll
      for (int ni = 0; ni < 4; ++ni)
#pragma unroll
        for (int r = 0; r < 4; ++r) {
          int grow = mbase + mi * 16 + quad * 4 + r;
          int b = grow >> 11, spos = grow & (SS - 1);
          int nv = cb + ni * 16 + l16 - (HID + 512);
          Vt[(((size_t)(b * NKV + (nv >> 6))) * HD + (nv & 63)) * SS + spos] =
              (bf16)acc[mi][ni][r];
        }
  } else {
    // Q or K: RoPE in fp32 regs; pairs (ni=0,ni=2) at freq l16, (1,3) at l16+16.
    const float inv0 = __builtin_amdgcn_exp2f(-(float)l16 * L2B);
    const float inv1 = __builtin_amdgcn_exp2f(-(float)(l16 + 16) * L2B);
#pragma unroll
    for (int mi = 0; mi < 8; ++mi) {
#pragma unroll
      for (int r = 0; r < 4; ++r) {
        int grow = mbase + mi * 16 + quad * 4 + r;
        int b = grow >> 11, spos = grow & (SS - 1);
        float sn0, cs0, sn1, cs1;
        sincosf((float)spos * inv0, &sn0, &cs0);
        sincosf((float)spos * inv1, &sn1, &cs1);
        float a0 = acc[mi][0][r], a1 = acc[mi][1][r];
        float a2 = acc[mi][2][r], a3 = acc[mi][3][r];
        float o0 = a0 * cs0 - a2 * sn0;
        float o2 = a2 * cs0 + a0 * sn0;
        float o1 = a1 * cs1 - a3 * sn1;
        float o3 = a3 * cs1 + a1 * sn1;
        if (mode == 0) {
          bf16* qp = Qb + (size_t)grow * HID + cb + l16;
          qp[0]  = (bf16)(o0 * QSCALE);
          qp[16] = (bf16)(o1 * QSCALE);
          qp[32] = (bf16)(o2 * QSCALE);
          qp[48] = (bf16)(o3 * QSCALE);
        } else {
          int kvh = (cb - HID) >> 6;
          bf16* kp = Kb + ((size_t)(b * NKV + kvh) * SS + spos) * HD + l16;
          kp[0]  = (bf16)o0;
          kp[16] = (bf16)o1;
          kp[32] = (bf16)o2;
          kp[48] = (bf16)o3;
        }
      }
    }
  }
}

// ---------------- output projection (verified R8/R10: BK=64 single-phase, 256 blocks) ----------------
__global__ __launch_bounds__(512, 2) void gemm_out(const bf16* __restrict__ A,
                                                   const bf16* __restrict__ Wo,
                                                   float* __restrict__ out) {
  __shared__ __align__(16) char lds[3 * 49152];  // 144 KB -> 1 WG/CU
  const int tileM = blockIdx.x * 256;
  const int n0 = blockIdx.y * 128;
  f32x4 acc[4][4];
#pragma unroll
  for (int i = 0; i < 4; ++i)
#pragma unroll
    for (int j = 0; j < 4; ++j) acc[i][j] = (f32x4){0.f, 0.f, 0.f, 0.f};

  gemm_core_k64((const char*)(A + (size_t)tileM * HID),
                (const char*)(Wo + (size_t)n0 * HID), lds, acc);

  const int tid = threadIdx.x;
  const int w = tid >> 6, lane = tid & 63;
  const int l16 = lane & 15, quad = lane >> 4;
  const int wr = w >> 1, wc = w & 1;
#pragma unroll
  for (int mi = 0; mi < 4; ++mi)
#pragma unroll
    for (int ni = 0; ni < 4; ++ni)
#pragma unroll
      for (int r = 0; r < 4; ++r) {
        int grow = tileM + wr * 64 + mi * 16 + quad * 4 + r;
        int gcol = n0 + wc * 64 + ni * 16 + l16;
        out[(size_t)grow * HID + gcol] = acc[mi][ni][r];
      }
}

// ---------------- flash attention v6: 128 q-rows per block (verified round 5) ----------------
#define PSTR 72
__global__ __launch_bounds__(256, 3) void attn(const bf16* __restrict__ Qb,
                                               const bf16* __restrict__ Kb,
                                               const bf16* __restrict__ Vt,
                                               bf16* __restrict__ Ctx) {
  __shared__ bf16 Ktile[2][64 * 64];
  __shared__ bf16 Vtile[2][64 * 64];
  __shared__ bf16 Pbuf[4][32 * PSTR];   // per wave: rows 0-15 = A, 16-31 = B
  const int tid = threadIdx.x;
  const int w = tid >> 6, lane = tid & 63;
  const int l16 = lane & 15, quad = lane >> 4;
  const int bh = blockIdx.y, b = bh >> 5, h = bh & 31, kvh = h >> 2;
  bf16* Pw = &Pbuf[w][0];
  const char* Kslice = (const char*)(Kb + ((size_t)(b * NKV + kvh)) * SS * HD);
  const char* Vslice = (const char*)(Vt + ((size_t)(b * NKV + kvh)) * HD * SS);
  const int qrel = w * 16 + l16;        // 0..63 within each 64-row subtile

  const int srow = (lane >> 3) & 7;
  const int pchunk = ((lane & 7) ^ srow) << 4;
  const int so = ((quad ^ (l16 & 7)) << 4);
  const int so2 = so ^ 64;

  const int xA = (int)blockIdx.x;       // 0..7

  int cur = 0;
  {
#pragma unroll
    for (int i = 0; i < 2; ++i) {
      const int r = w * 16 + i * 8 + srow;
      load_lds16(Kslice + (size_t)r * 128 + pchunk,
                 (char*)Ktile[0] + (w * 16 + i * 8) * 128);
      load_lds16(Vslice + (size_t)r * 4096 + pchunk,
                 (char*)Vtile[0] + (w * 16 + i * 8) * 128);
    }
  }

  for (int t = 0; t < 2; ++t) {
    const int X = t ? (15 - xA) : xA;   // 128-row superblock index
    const int qA = X * 128 + qrel;
    const int ktmax = 2 * X + 1;        // last kv tile (64 keys each)

    const bf16* QpA = Qb + ((size_t)(b * SS + qA)) * HID + h * HD + quad * 8;
    bf16x8 qa0 = *(const bf16x8*)QpA;
    bf16x8 qa1 = *(const bf16x8*)(QpA + 32);
    const bf16* QpB = QpA + (size_t)64 * HID;
    bf16x8 qbB0 = *(const bf16x8*)QpB;
    bf16x8 qbB1 = *(const bf16x8*)(QpB + 32);

    float lA = 0.f, lB = 0.f;
    f32x4 oA[4], oB[4];
#pragma unroll
    for (int d = 0; d < 4; ++d) {
      oA[d] = (f32x4){0.f, 0.f, 0.f, 0.f};
      oB[d] = (f32x4){0.f, 0.f, 0.f, 0.f};
    }

    for (int kt = 0; kt <= ktmax; ++kt) {
      __syncthreads();   // cur tile ready (staged a full compute phase ago)

      const bool have_next = (kt < ktmax) || (t == 0);
      if (have_next) {
        const int nkb = (kt < ktmax) ? (kt + 1) * 64 : 0;  // last: tile 0 for pass 1
        const int nb = cur ^ 1;
#pragma unroll
        for (int i = 0; i < 2; ++i) {
          const int r = w * 16 + i * 8 + srow;
          load_lds16(Kslice + (size_t)(nkb + r) * 128 + pchunk,
                     (char*)Ktile[nb] + (w * 16 + i * 8) * 128);
          load_lds16(Vslice + (size_t)r * 4096 + (size_t)nkb * 2 + pchunk,
                     (char*)Vtile[nb] + (w * 16 + i * 8) * 128);
        }
      }

      const char* Kc = (const char*)Ktile[cur] + l16 * 128;
      const char* Vc = (const char*)Vtile[cur] + l16 * 128;
      const bool skipA = (kt == ktmax);       // A fully masked on last tile
      const bool diagA = (kt == ktmax - 1);   // kt == 2X
      const bool diagB = (kt == ktmax);       // kt == 2X+1

#pragma unroll
      for (int nt = 0; nt < 4; ++nt) {
        bf16x8 kf0 = *(const bf16x8*)(Kc + nt * 2048 + so);
        bf16x8 kf1 = *(const bf16x8*)(Kc + nt * 2048 + so2);
        const int krel = nt * 16 + quad * 4;

        bf16x4 pkA;
        if (skipA) {
          pkA[0] = (bf16)0.f; pkA[1] = (bf16)0.f;
          pkA[2] = (bf16)0.f; pkA[3] = (bf16)0.f;
        } else {
          f32x4 s = {0.f, 0.f, 0.f, 0.f};
          s = MFMA16(kf0, qa0, s);   // S^T: row = key, col = q (l16)
          s = MFMA16(kf1, qa1, s);
          if (diagA) {
#pragma unroll
            for (int r = 0; r < 4; ++r) {
              float p = (krel + r > qrel) ? 0.f : __builtin_amdgcn_exp2f(s[r]);
              lA += p;
              pkA[r] = (bf16)p;
            }
          } else {
#pragma unroll
            for (int r = 0; r < 4; ++r) {
              float p = __builtin_amdgcn_exp2f(s[r]);
              lA += p;
              pkA[r] = (bf16)p;
            }
          }
        }
        *(bf16x4*)&Pw[l16 * PSTR + krel] = pkA;

        f32x4 sB = {0.f, 0.f, 0.f, 0.f};
        sB = MFMA16(kf0, qbB0, sB);
        sB = MFMA16(kf1, qbB1, sB);
        bf16x4 pkB;
        if (diagB) {
#pragma unroll
          for (int r = 0; r < 4; ++r) {
            float p = (krel + r > qrel) ? 0.f : __builtin_amdgcn_exp2f(sB[r]);
            lB += p;
            pkB[r] = (bf16)p;
          }
        } else {
#pragma unroll
          for (int r = 0; r < 4; ++r) {
            float p = __builtin_amdgcn_exp2f(sB[r]);
            lB += p;
            pkB[r] = (bf16)p;
          }
        }
        *(bf16x4*)&Pw[(16 + l16) * PSTR + krel] = pkB;
      }

      bf16x8 pA0 = *(const bf16x8*)&Pw[l16 * PSTR + quad * 8];
      bf16x8 pA1 = *(const bf16x8*)&Pw[l16 * PSTR + 32 + quad * 8];
      bf16x8 pB0 = *(const bf16x8*)&Pw[(16 + l16) * PSTR + quad * 8];
      bf16x8 pB1 = *(const bf16x8*)&Pw[(16 + l16) * PSTR + 32 + quad * 8];
#pragma unroll
      for (int dn = 0; dn < 4; ++dn) {
        bf16x8 v0 = *(const bf16x8*)(Vc + dn * 2048 + so);
        bf16x8 v1 = *(const bf16x8*)(Vc + dn * 2048 + so2);
        oA[dn] = MFMA16(v0, pA0, oA[dn]);  // O^T: row = d, col = q
        oA[dn] = MFMA16(v1, pA1, oA[dn]);
        oB[dn] = MFMA16(v0, pB0, oB[dn]);
        oB[dn] = MFMA16(v1, pB1, oB[dn]);
      }
      cur ^= 1;
    }

    lA += __shfl_xor(lA, 16);
    lA += __shfl_xor(lA, 32);
    lB += __shfl_xor(lB, 16);
    lB += __shfl_xor(lB, 32);
    const float invA = 1.0f / lA;
    const float invB = 1.0f / lB;
    bf16* CpA = Ctx + ((size_t)(b * SS + qA)) * HID + h * HD + quad * 4;
    bf16* CpB = CpA + (size_t)64 * HID;
#pragma unroll
    for (int dn = 0; dn < 4; ++dn) {
      bf16x4 ovA, ovB;
#pragma unroll
      for (int r = 0; r < 4; ++r) {
        ovA[r] = (bf16)(oA[dn][r] * invA);
        ovB[r] = (bf16)(oB[dn][r] * invB);
      }
      *(bf16x4*)(CpA + dn * 16) = ovA;
      *(bf16x4*)(CpB + dn * 16) = ovB;
    }
  }
}

// ---------------- launch ----------------
extern "C" void kernel_launch(void* const* d_in, const int* in_sizes, int n_in,
                              void* d_out, int out_size, void* d_ws, size_t ws_size,
                              hipStream_t stream) {
  const float* hs = (const float*)d_in[0];
  const float* Wq = (const float*)d_in[2];
  const float* Wk = (const float*)d_in[3];
  const float* Wv = (const float*)d_in[4];
  const float* Wo = (const float*)d_in[5];

  char* ws = (char*)d_ws;
  bf16* A_b  = (bf16*)(ws);              // 16 MB ; reused as Ctx after QKV gemm
  bf16* Wq_b = (bf16*)(ws + 16777216);   // 8 MB
  bf16* Wk_b = (bf16*)(ws + 25165824);   // 2 MB
  bf16* Wv_b = (bf16*)(ws + 27262976);   // 2 MB
  bf16* Wo_b = (bf16*)(ws + 29360128);   // 8 MB
  bf16* Qb   = (bf16*)(ws + 37748736);   // 16 MB
  bf16* Kb   = (bf16*)(ws + 54525952);   // 4 MB
  bf16* Vt   = (bf16*)(ws + 58720256);   // 4 MB  (end: 62914560)
  bf16* Ctx  = A_b;

  cvt_all<<<18432, 256, 0, stream>>>(hs, Wq, Wk, Wv, Wo, A_b, Wq_b, Wk_b, Wv_b, Wo_b);
  gemm_qkv<<<dim3(MTOT / 256, 24), 256, 0, stream>>>(A_b, Wq_b, Wk_b, Wv_b, Qb, Kb, Vt);
  attn<<<dim3(8, BB * NH), 256, 0, stream>>>(Qb, Kb, Vt, Ctx);
  gemm_out<<<dim3(MTOT / 256, HID / 128), 512, 0, stream>>>(Ctx, Wo_b, (float*)d_out);
}

// Round 12
// 295.562 us; speedup vs baseline: 1.0682x; 1.0682x over previous
//
#include <hip/hip_runtime.h>
#include <math.h>

#define HID 2048
#define NH 32
#define NKV 8
#define HD 64
#define BB 2
#define SS 2048
#define MTOT (BB * SS) // 4096

typedef __bf16 bf16;
typedef __bf16 bf16x8 __attribute__((ext_vector_type(8)));
typedef __bf16 bf16x4 __attribute__((ext_vector_type(4)));
typedef float f32x4 __attribute__((ext_vector_type(4)));

#define MFMA16(a, b, c) __builtin_amdgcn_mfma_f32_16x16x32_bf16((a), (b), (c), 0, 0, 0)

__device__ __forceinline__ void load_lds16(const void* g, void* l) {
  __builtin_amdgcn_global_load_lds((const __attribute__((address_space(1))) void*)g,
                                   (__attribute__((address_space(3))) void*)l, 16, 0, 0);
}

#define FENCE() asm volatile("" ::: "memory")
// Tile-top sync: counted vmcnt (never 0 in main loop) + lgkmcnt(0) so this
// wave's ds_reads have COMPLETED before it enters the barrier (orders them
// against other waves' post-barrier global_load_lds writebacks), then barrier.
#define SYNC_VM(N) do { FENCE(); \
  asm volatile("s_waitcnt vmcnt(" #N ") lgkmcnt(0)" ::: "memory"); \
  __builtin_amdgcn_s_barrier(); FENCE(); } while (0)

// ---------------- fused fp32 -> bf16 convert (EXACT R0 version - fastest measured) ----------------
// R8/R9/R10 A/B: all cvt variants within ~3 us; this one is the best. Leave alone.
__global__ void cvt_all(const float* __restrict__ hs, const float* __restrict__ Wq,
                        const float* __restrict__ Wk, const float* __restrict__ Wv,
                        const float* __restrict__ Wo,
                        bf16* __restrict__ A_b, bf16* __restrict__ Wq_b,
                        bf16* __restrict__ Wk_b, bf16* __restrict__ Wv_b,
                        bf16* __restrict__ Wo_b) {
  int bid = blockIdx.x;
  const float* src;
  bf16* dst;
  if (bid < 8192)       { src = hs; dst = A_b; }
  else if (bid < 12288) { src = Wq; dst = Wq_b; bid -= 8192; }
  else if (bid < 13312) { src = Wk; dst = Wk_b; bid -= 12288; }
  else if (bid < 14336) { src = Wv; dst = Wv_b; bid -= 13312; }
  else                  { src = Wo; dst = Wo_b; bid -= 14336; }
  int i = (bid * 256 + threadIdx.x) * 4;
  float4 v = *(const float4*)(src + i);
  bf16x4 o;
  o[0] = (bf16)v.x; o[1] = (bf16)v.y; o[2] = (bf16)v.z; o[3] = (bf16)v.w;
  *(bf16x4*)(dst + i) = o;
}

// ---------------- BK=32 pipelined core (verified R4/R5/R10): 256x128, 8 waves ----------------
// 72 KB -> 2 WG/CU (16 waves). acc[4][4]=64 regs: no spill (VGPR 56).
// NOTE (R1, R11): per-wave 128x64 / acc[8][4] variants SPILL (WRITE_SIZE
// 24.6 -> 123 MB, qkv +35 us) -- the compiler won't allocate a 128-element
// accumulator in this structure. Retired; do not retry.
__device__ __forceinline__ void gemm_core256x128(const char* Agc, const char* Bgc,
                                                 char* lds, f32x4 (&acc)[4][4]) {
  constexpr int ABYTES = 16384;     // A tile bytes (256 x 32 bf16)
  constexpr int BUFB = 24576;       // + B tile (128 x 32 bf16)
  constexpr int NT = HID / 32;      // 64 K-tiles

  const int tid = threadIdx.x;
  const int w = tid >> 6, lane = tid & 63;
  const int l16 = lane & 15, quad = lane >> 4;
  const int wr = w >> 1, wc = w & 1;
  const int wb = w * 1024;          // wave-uniform LDS staging base

  const int cu = (tid & 7) ^ ((tid >> 3) & 7);
  const int srcR0 = 2 * (tid >> 3) + (cu >> 2);   // 0..127
  const int srcC = (cu & 3) * 16;
  const char* gA = Agc + (size_t)srcR0 * (HID * 2) + srcC;
  const char* gB = Bgc + (size_t)srcR0 * (HID * 2) + srcC;

  const int acg16 = ((((l16 & 1) << 2) | quad) ^ ((l16 >> 1) & 7)) * 16;
  const int aoff = (wr * 32 + (l16 >> 1)) * 128 + acg16;
  const int boff = ABYTES + (wc * 32 + (l16 >> 1)) * 128 + acg16;

#pragma unroll
  for (int t0 = 0; t0 < 2; ++t0) {
    char* lb = lds + t0 * BUFB;
    load_lds16(gA + t0 * 64, lb + wb);
    load_lds16(gA + (size_t)128 * (HID * 2) + t0 * 64, lb + 8192 + wb);
    load_lds16(gB + t0 * 64, lb + ABYTES + wb);
  }

  char* cur = lds;
  char* stg = lds + 2 * BUFB;
  for (int kt = 0; kt < NT; ++kt) {
    SYNC_VM(3);
    const int ks = (kt + 2 < NT) ? (kt + 2) * 64 : (NT - 1) * 64;

    load_lds16(gA + ks, stg + wb);
    load_lds16(gA + (size_t)128 * (HID * 2) + ks, stg + 8192 + wb);
    load_lds16(gB + ks, stg + ABYTES + wb);
    FENCE();

    bf16x8 af[4], bfr[4];
#pragma unroll
    for (int ni = 0; ni < 4; ++ni)
      bfr[ni] = *(const bf16x8*)(cur + boff + ni * 1024);
#pragma unroll
    for (int mi = 0; mi < 4; ++mi)
      af[mi] = *(const bf16x8*)(cur + aoff + mi * 1024);
    __builtin_amdgcn_s_setprio(1);
#pragma unroll
    for (int mi = 0; mi < 4; ++mi)
#pragma unroll
      for (int ni = 0; ni < 4; ++ni)
        acc[mi][ni] = MFMA16(af[mi], bfr[ni], acc[mi][ni]);
    __builtin_amdgcn_s_setprio(0);

    cur = (cur == lds + 2 * BUFB) ? lds : cur + BUFB;
    stg = (stg == lds + 2 * BUFB) ? lds : stg + BUFB;
  }
  asm volatile("s_waitcnt vmcnt(0)" ::: "memory");
}

// ---------------- BK=64 single-phase core (verified R6/R8/R10; gemm_out only) ----------------
__device__ __forceinline__ void gemm_core_k64(const char* Agc, const char* Bgc,
                                              char* lds, f32x4 (&acc)[4][4]) {
  constexpr int ABYTES = 32768;   // A tile: 256 rows x 64 cols bf16
  constexpr int BUFB = 49152;     // + B tile: 128 rows x 64 cols bf16
  constexpr int NT = HID / 64;    // 32 K-steps

  const int tid = threadIdx.x;
  const int w = tid >> 6, lane = tid & 63;
  const int l16 = lane & 15, quad = lane >> 4;
  const int wr = w >> 1, wc = w & 1;
  const int wb = w * 1024;        // wave-uniform LDS staging base

  const int cu = (lane & 7) ^ ((lane >> 3) & 7);
  const char* gA = Agc + (size_t)(w * 8 + (lane >> 3)) * 4096 + cu * 16;
  const char* gB = Bgc + (size_t)(w * 8 + (lane >> 3)) * 4096 + cu * 16;

  const int aswz = l16 & 7;
  const int a_k0 = ((0 + quad) ^ aswz) * 16;   // ks = 0
  const int a_k1 = ((4 + quad) ^ aswz) * 16;   // ks = 1
  const int arow = (wr * 64 + l16) * 128;
  const int brow = (wc * 64 + l16) * 128;

#pragma unroll
  for (int t0 = 0; t0 < 2; ++t0) {
    char* lb = lds + t0 * BUFB;
#pragma unroll
    for (int j = 0; j < 4; ++j)
      load_lds16(gA + (size_t)j * (64 * 4096) + t0 * 128, lb + wb + j * 8192);
#pragma unroll
    for (int j = 0; j < 2; ++j)
      load_lds16(gB + (size_t)j * (64 * 4096) + t0 * 128, lb + ABYTES + wb + j * 8192);
  }

  char* cur = lds;
  char* stg = lds + 2 * BUFB;
  for (int kt = 0; kt < NT; ++kt) {
    SYNC_VM(6);
    const int ks = (kt + 2 < NT) ? (kt + 2) : (NT - 1);
    const size_t ko = (size_t)ks * 128;

#pragma unroll
    for (int j = 0; j < 4; ++j)
      load_lds16(gA + (size_t)j * (64 * 4096) + ko, stg + wb + j * 8192);
#pragma unroll
    for (int j = 0; j < 2; ++j)
      load_lds16(gB + (size_t)j * (64 * 4096) + ko, stg + ABYTES + wb + j * 8192);
    FENCE();

    const char* Ac = cur;
    const char* Bc = cur + ABYTES;
    bf16x8 af0[4], af1[4], bf0[4], bf1[4];
#pragma unroll
    for (int ni = 0; ni < 4; ++ni) {
      bf0[ni] = *(const bf16x8*)(Bc + brow + ni * 2048 + a_k0);
      bf1[ni] = *(const bf16x8*)(Bc + brow + ni * 2048 + a_k1);
    }
#pragma unroll
    for (int mi = 0; mi < 4; ++mi) {
      af0[mi] = *(const bf16x8*)(Ac + arow + mi * 2048 + a_k0);
      af1[mi] = *(const bf16x8*)(Ac + arow + mi * 2048 + a_k1);
    }
    __builtin_amdgcn_s_setprio(1);
#pragma unroll
    for (int mi = 0; mi < 4; ++mi)
#pragma unroll
      for (int ni = 0; ni < 4; ++ni) {
        acc[mi][ni] = MFMA16(af0[mi], bf0[ni], acc[mi][ni]);
        acc[mi][ni] = MFMA16(af1[mi], bf1[ni], acc[mi][ni]);
      }
    __builtin_amdgcn_s_setprio(0);

    cur = (cur == lds + 2 * BUFB) ? lds : cur + BUFB;
    stg = (stg == lds + 2 * BUFB) ? lds : stg + BUFB;
  }
  asm volatile("s_waitcnt vmcnt(0)" ::: "memory");
}

// ---------------- fused QKV projection + RoPE epilogue (verified R5/R7/R10) ----------------
#define QSCALE 0.1803368801f
#define L2B 0.4152410118f  // log2(10000)/32
__global__ __launch_bounds__(512, 4) void gemm_qkv(const bf16* __restrict__ A,
                                                   const bf16* __restrict__ Wq,
                                                   const bf16* __restrict__ Wk,
                                                   const bf16* __restrict__ Wv,
                                                   bf16* __restrict__ Qb,
                                                   bf16* __restrict__ Kb,
                                                   bf16* __restrict__ Vt) {
  __shared__ __align__(16) char lds[3 * 24576];  // 72 KB -> 2 WG/CU (16 waves)
  const int tileM = blockIdx.x * 256;
  const int n0 = blockIdx.y * 128;
  const bf16* Wp;
  int mode;
  if (n0 < HID) { Wp = Wq + (size_t)n0 * HID; mode = 0; }
  else if (n0 < HID + 512) { Wp = Wk + (size_t)(n0 - HID) * HID; mode = 1; }
  else { Wp = Wv + (size_t)(n0 - HID - 512) * HID; mode = 2; }

  f32x4 acc[4][4];
#pragma unroll
  for (int i = 0; i < 4; ++i)
#pragma unroll
    for (int j = 0; j < 4; ++j) acc[i][j] = (f32x4){0.f, 0.f, 0.f, 0.f};

  gemm_core256x128((const char*)(A + (size_t)tileM * HID), (const char*)Wp, lds, acc);

  const int tid = threadIdx.x;
  const int w = tid >> 6, lane = tid & 63;
  const int l16 = lane & 15, quad = lane >> 4;
  const int wr = w >> 1, wc = w & 1;
  const int mbase = tileM + wr * 64;
  const int cb = n0 + wc * 64;  // 64-aligned -> wave col span = one head

  if (mode == 2) {
    // V: transposed layout [b,kvh,d,s]
#pragma unroll
    for (int mi = 0; mi < 4; ++mi)
#pragma unroll
      for (int ni = 0; ni < 4; ++ni)
#pragma unroll
        for (int r = 0; r < 4; ++r) {
          int grow = mbase + mi * 16 + quad * 4 + r;
          int b = grow >> 11, spos = grow & (SS - 1);
          int nv = cb + ni * 16 + l16 - (HID + 512);
          Vt[(((size_t)(b * NKV + (nv >> 6))) * HD + (nv & 63)) * SS + spos] =
              (bf16)acc[mi][ni][r];
        }
  } else {
    // Q or K: RoPE in fp32 regs; pairs (ni=0,ni=2) at freq l16, (1,3) at l16+16.
    const float inv0 = __builtin_amdgcn_exp2f(-(float)l16 * L2B);
    const float inv1 = __builtin_amdgcn_exp2f(-(float)(l16 + 16) * L2B);
#pragma unroll
    for (int mi = 0; mi < 4; ++mi) {
#pragma unroll
      for (int r = 0; r < 4; ++r) {
        int grow = mbase + mi * 16 + quad * 4 + r;
        int b = grow >> 11, spos = grow & (SS - 1);
        float sn0, cs0, sn1, cs1;
        sincosf((float)spos * inv0, &sn0, &cs0);
        sincosf((float)spos * inv1, &sn1, &cs1);
        float a0 = acc[mi][0][r], a1 = acc[mi][1][r];
        float a2 = acc[mi][2][r], a3 = acc[mi][3][r];
        float o0 = a0 * cs0 - a2 * sn0;
        float o2 = a2 * cs0 + a0 * sn0;
        float o1 = a1 * cs1 - a3 * sn1;
        float o3 = a3 * cs1 + a1 * sn1;
        if (mode == 0) {
          bf16* qp = Qb + (size_t)grow * HID + cb + l16;
          qp[0]  = (bf16)(o0 * QSCALE);
          qp[16] = (bf16)(o1 * QSCALE);
          qp[32] = (bf16)(o2 * QSCALE);
          qp[48] = (bf16)(o3 * QSCALE);
        } else {
          int kvh = (cb - HID) >> 6;
          bf16* kp = Kb + ((size_t)(b * NKV + kvh) * SS + spos) * HD + l16;
          kp[0]  = (bf16)o0;
          kp[16] = (bf16)o1;
          kp[32] = (bf16)o2;
          kp[48] = (bf16)o3;
        }
      }
    }
  }
}

// ---------------- output projection (verified R8/R10: BK=64 single-phase, 256 blocks) ----------------
__global__ __launch_bounds__(512, 2) void gemm_out(const bf16* __restrict__ A,
                                                   const bf16* __restrict__ Wo,
                                                   float* __restrict__ out) {
  __shared__ __align__(16) char lds[3 * 49152];  // 144 KB -> 1 WG/CU
  const int tileM = blockIdx.x * 256;
  const int n0 = blockIdx.y * 128;
  f32x4 acc[4][4];
#pragma unroll
  for (int i = 0; i < 4; ++i)
#pragma unroll
    for (int j = 0; j < 4; ++j) acc[i][j] = (f32x4){0.f, 0.f, 0.f, 0.f};

  gemm_core_k64((const char*)(A + (size_t)tileM * HID),
                (const char*)(Wo + (size_t)n0 * HID), lds, acc);

  const int tid = threadIdx.x;
  const int w = tid >> 6, lane = tid & 63;
  const int l16 = lane & 15, quad = lane >> 4;
  const int wr = w >> 1, wc = w & 1;
#pragma unroll
  for (int mi = 0; mi < 4; ++mi)
#pragma unroll
    for (int ni = 0; ni < 4; ++ni)
#pragma unroll
      for (int r = 0; r < 4; ++r) {
        int grow = tileM + wr * 64 + mi * 16 + quad * 4 + r;
        int gcol = n0 + wc * 64 + ni * 16 + l16;
        out[(size_t)grow * HID + gcol] = acc[mi][ni][r];
      }
}

// ---------------- flash attention v6 + T5 setprio around MFMA clusters ----------------
// Structure verified R5-R10. New: s_setprio(1) around the QK^T MFMA pairs and
// the PV MFMA loop (m191: +4-7% for independent attn blocks; no sync change).
#define PSTR 72
__global__ __launch_bounds__(256, 3) void attn(const bf16* __restrict__ Qb,
                                               const bf16* __restrict__ Kb,
                                               const bf16* __restrict__ Vt,
                                               bf16* __restrict__ Ctx) {
  __shared__ bf16 Ktile[2][64 * 64];
  __shared__ bf16 Vtile[2][64 * 64];
  __shared__ bf16 Pbuf[4][32 * PSTR];   // per wave: rows 0-15 = A, 16-31 = B
  const int tid = threadIdx.x;
  const int w = tid >> 6, lane = tid & 63;
  const int l16 = lane & 15, quad = lane >> 4;
  const int bh = blockIdx.y, b = bh >> 5, h = bh & 31, kvh = h >> 2;
  bf16* Pw = &Pbuf[w][0];
  const char* Kslice = (const char*)(Kb + ((size_t)(b * NKV + kvh)) * SS * HD);
  const char* Vslice = (const char*)(Vt + ((size_t)(b * NKV + kvh)) * HD * SS);
  const int qrel = w * 16 + l16;        // 0..63 within each 64-row subtile

  const int srow = (lane >> 3) & 7;
  const int pchunk = ((lane & 7) ^ srow) << 4;
  const int so = ((quad ^ (l16 & 7)) << 4);
  const int so2 = so ^ 64;

  const int xA = (int)blockIdx.x;       // 0..7

  int cur = 0;
  {
#pragma unroll
    for (int i = 0; i < 2; ++i) {
      const int r = w * 16 + i * 8 + srow;
      load_lds16(Kslice + (size_t)r * 128 + pchunk,
                 (char*)Ktile[0] + (w * 16 + i * 8) * 128);
      load_lds16(Vslice + (size_t)r * 4096 + pchunk,
                 (char*)Vtile[0] + (w * 16 + i * 8) * 128);
    }
  }

  for (int t = 0; t < 2; ++t) {
    const int X = t ? (15 - xA) : xA;   // 128-row superblock index
    const int qA = X * 128 + qrel;
    const int ktmax = 2 * X + 1;        // last kv tile (64 keys each)

    const bf16* QpA = Qb + ((size_t)(b * SS + qA)) * HID + h * HD + quad * 8;
    bf16x8 qa0 = *(const bf16x8*)QpA;
    bf16x8 qa1 = *(const bf16x8*)(QpA + 32);
    const bf16* QpB = QpA + (size_t)64 * HID;
    bf16x8 qbB0 = *(const bf16x8*)QpB;
    bf16x8 qbB1 = *(const bf16x8*)(QpB + 32);

    float lA = 0.f, lB = 0.f;
    f32x4 oA[4], oB[4];
#pragma unroll
    for (int d = 0; d < 4; ++d) {
      oA[d] = (f32x4){0.f, 0.f, 0.f, 0.f};
      oB[d] = (f32x4){0.f, 0.f, 0.f, 0.f};
    }

    for (int kt = 0; kt <= ktmax; ++kt) {
      __syncthreads();   // cur tile ready (staged a full compute phase ago)

      const bool have_next = (kt < ktmax) || (t == 0);
      if (have_next) {
        const int nkb = (kt < ktmax) ? (kt + 1) * 64 : 0;  // last: tile 0 for pass 1
        const int nb = cur ^ 1;
#pragma unroll
        for (int i = 0; i < 2; ++i) {
          const int r = w * 16 + i * 8 + srow;
          load_lds16(Kslice + (size_t)(nkb + r) * 128 + pchunk,
                     (char*)Ktile[nb] + (w * 16 + i * 8) * 128);
          load_lds16(Vslice + (size_t)r * 4096 + (size_t)nkb * 2 + pchunk,
                     (char*)Vtile[nb] + (w * 16 + i * 8) * 128);
        }
      }

      const char* Kc = (const char*)Ktile[cur] + l16 * 128;
      const char* Vc = (const char*)Vtile[cur] + l16 * 128;
      const bool skipA = (kt == ktmax);       // A fully masked on last tile
      const bool diagA = (kt == ktmax - 1);   // kt == 2X
      const bool diagB = (kt == ktmax);       // kt == 2X+1

#pragma unroll
      for (int nt = 0; nt < 4; ++nt) {
        bf16x8 kf0 = *(const bf16x8*)(Kc + nt * 2048 + so);
        bf16x8 kf1 = *(const bf16x8*)(Kc + nt * 2048 + so2);
        const int krel = nt * 16 + quad * 4;

        bf16x4 pkA;
        if (skipA) {
          pkA[0] = (bf16)0.f; pkA[1] = (bf16)0.f;
          pkA[2] = (bf16)0.f; pkA[3] = (bf16)0.f;
        } else {
          f32x4 s = {0.f, 0.f, 0.f, 0.f};
          __builtin_amdgcn_s_setprio(1);
          s = MFMA16(kf0, qa0, s);   // S^T: row = key, col = q (l16)
          s = MFMA16(kf1, qa1, s);
          __builtin_amdgcn_s_setprio(0);
          if (diagA) {
#pragma unroll
            for (int r = 0; r < 4; ++r) {
              float p = (krel + r > qrel) ? 0.f : __builtin_amdgcn_exp2f(s[r]);
              lA += p;
              pkA[r] = (bf16)p;
            }
          } else {
#pragma unroll
            for (int r = 0; r < 4; ++r) {
              float p = __builtin_amdgcn_exp2f(s[r]);
              lA += p;
              pkA[r] = (bf16)p;
            }
          }
        }
        *(bf16x4*)&Pw[l16 * PSTR + krel] = pkA;

        f32x4 sB = {0.f, 0.f, 0.f, 0.f};
        __builtin_amdgcn_s_setprio(1);
        sB = MFMA16(kf0, qbB0, sB);
        sB = MFMA16(kf1, qbB1, sB);
        __builtin_amdgcn_s_setprio(0);
        bf16x4 pkB;
        if (diagB) {
#pragma unroll
          for (int r = 0; r < 4; ++r) {
            float p = (krel + r > qrel) ? 0.f : __builtin_amdgcn_exp2f(sB[r]);
            lB += p;
            pkB[r] = (bf16)p;
          }
        } else {
#pragma unroll
          for (int r = 0; r < 4; ++r) {
            float p = __builtin_amdgcn_exp2f(sB[r]);
            lB += p;
            pkB[r] = (bf16)p;
          }
        }
        *(bf16x4*)&Pw[(16 + l16) * PSTR + krel] = pkB;
      }

      bf16x8 pA0 = *(const bf16x8*)&Pw[l16 * PSTR + quad * 8];
      bf16x8 pA1 = *(const bf16x8*)&Pw[l16 * PSTR + 32 + quad * 8];
      bf16x8 pB0 = *(const bf16x8*)&Pw[(16 + l16) * PSTR + quad * 8];
      bf16x8 pB1 = *(const bf16x8*)&Pw[(16 + l16) * PSTR + 32 + quad * 8];
      __builtin_amdgcn_s_setprio(1);
#pragma unroll
      for (int dn = 0; dn < 4; ++dn) {
        bf16x8 v0 = *(const bf16x8*)(Vc + dn * 2048 + so);
        bf16x8 v1 = *(const bf16x8*)(Vc + dn * 2048 + so2);
        oA[dn] = MFMA16(v0, pA0, oA[dn]);  // O^T: row = d, col = q
        oA[dn] = MFMA16(v1, pA1, oA[dn]);
        oB[dn] = MFMA16(v0, pB0, oB[dn]);
        oB[dn] = MFMA16(v1, pB1, oB[dn]);
      }
      __builtin_amdgcn_s_setprio(0);
      cur ^= 1;
    }

    lA += __shfl_xor(lA, 16);
    lA += __shfl_xor(lA, 32);
    lB += __shfl_xor(lB, 16);
    lB += __shfl_xor(lB, 32);
    const float invA = 1.0f / lA;
    const float invB = 1.0f / lB;
    bf16* CpA = Ctx + ((size_t)(b * SS + qA)) * HID + h * HD + quad * 4;
    bf16* CpB = CpA + (size_t)64 * HID;
#pragma unroll
    for (int dn = 0; dn < 4; ++dn) {
      bf16x4 ovA, ovB;
#pragma unroll
      for (int r = 0; r < 4; ++r) {
        ovA[r] = (bf16)(oA[dn][r] * invA);
        ovB[r] = (bf16)(oB[dn][r] * invB);
      }
      *(bf16x4*)(CpA + dn * 16) = ovA;
      *(bf16x4*)(CpB + dn * 16) = ovB;
    }
  }
}

// ---------------- launch ----------------
extern "C" void kernel_launch(void* const* d_in, const int* in_sizes, int n_in,
                              void* d_out, int out_size, void* d_ws, size_t ws_size,
                              hipStream_t stream) {
  const float* hs = (const float*)d_in[0];
  const float* Wq = (const float*)d_in[2];
  const float* Wk = (const float*)d_in[3];
  const float* Wv = (const float*)d_in[4];
  const float* Wo = (const float*)d_in[5];

  char* ws = (char*)d_ws;
  bf16* A_b  = (bf16*)(ws);              // 16 MB ; reused as Ctx after QKV gemm
  bf16* Wq_b = (bf16*)(ws + 16777216);   // 8 MB
  bf16* Wk_b = (bf16*)(ws + 25165824);   // 2 MB
  bf16* Wv_b = (bf16*)(ws + 27262976);   // 2 MB
  bf16* Wo_b = (bf16*)(ws + 29360128);   // 8 MB
  bf16* Qb   = (bf16*)(ws + 37748736);   // 16 MB
  bf16* Kb   = (bf16*)(ws + 54525952);   // 4 MB
  bf16* Vt   = (bf16*)(ws + 58720256);   // 4 MB  (end: 62914560)
  bf16* Ctx  = A_b;

  cvt_all<<<18432, 256, 0, stream>>>(hs, Wq, Wk, Wv, Wo, A_b, Wq_b, Wk_b, Wv_b, Wo_b);
  gemm_qkv<<<dim3(MTOT / 256, 24), 512, 0, stream>>>(A_b, Wq_b, Wk_b, Wv_b, Qb, Kb, Vt);
  attn<<<dim3(8, BB * NH), 256, 0, stream>>>(Qb, Kb, Vt, Ctx);
  gemm_out<<<dim3(MTOT / 256, HID / 128), 512, 0, stream>>>(Ctx, Wo_b, (float*)d_out);
}

// Round 13
// 294.011 us; speedup vs baseline: 1.0738x; 1.0053x over previous
//
#include <hip/hip_runtime.h>
#include <math.h>

#define HID 2048
#define NH 32
#define NKV 8
#define HD 64
#define BB 2
#define SS 2048
#define MTOT (BB * SS) // 4096

typedef __bf16 bf16;
typedef __bf16 bf16x8 __attribute__((ext_vector_type(8)));
typedef __bf16 bf16x4 __attribute__((ext_vector_type(4)));
typedef float f32x4 __attribute__((ext_vector_type(4)));

#define MFMA16(a, b, c) __builtin_amdgcn_mfma_f32_16x16x32_bf16((a), (b), (c), 0, 0, 0)

__device__ __forceinline__ void load_lds16(const void* g, void* l) {
  __builtin_amdgcn_global_load_lds((const __attribute__((address_space(1))) void*)g,
                                   (__attribute__((address_space(3))) void*)l, 16, 0, 0);
}

#define FENCE() asm volatile("" ::: "memory")
// Tile-top sync: counted vmcnt (never 0 in main loop) + lgkmcnt(0) so this
// wave's ds_reads have COMPLETED before it enters the barrier (orders them
// against other waves' post-barrier global_load_lds writebacks), then barrier.
#define SYNC_VM(N) do { FENCE(); \
  asm volatile("s_waitcnt vmcnt(" #N ") lgkmcnt(0)" ::: "memory"); \
  __builtin_amdgcn_s_barrier(); FENCE(); } while (0)

// ---------------- fused fp32 -> bf16 convert (EXACT R0 version - fastest measured) ----------------
// R8/R9/R10 A/B: all cvt variants within ~3 us; this one is the best. Leave alone.
__global__ void cvt_all(const float* __restrict__ hs, const float* __restrict__ Wq,
                        const float* __restrict__ Wk, const float* __restrict__ Wv,
                        const float* __restrict__ Wo,
                        bf16* __restrict__ A_b, bf16* __restrict__ Wq_b,
                        bf16* __restrict__ Wk_b, bf16* __restrict__ Wv_b,
                        bf16* __restrict__ Wo_b) {
  int bid = blockIdx.x;
  const float* src;
  bf16* dst;
  if (bid < 8192)       { src = hs; dst = A_b; }
  else if (bid < 12288) { src = Wq; dst = Wq_b; bid -= 8192; }
  else if (bid < 13312) { src = Wk; dst = Wk_b; bid -= 12288; }
  else if (bid < 14336) { src = Wv; dst = Wv_b; bid -= 13312; }
  else                  { src = Wo; dst = Wo_b; bid -= 14336; }
  int i = (bid * 256 + threadIdx.x) * 4;
  float4 v = *(const float4*)(src + i);
  bf16x4 o;
  o[0] = (bf16)v.x; o[1] = (bf16)v.y; o[2] = (bf16)v.z; o[3] = (bf16)v.w;
  *(bf16x4*)(dst + i) = o;
}

// ---------------- BK=32 pipelined core (verified R4/R5/R10): 256x128, 8 waves ----------------
// 72 KB -> 2 WG/CU (16 waves). acc[4][4]=64 regs: no spill (VGPR 56).
// NOTE (R1, R11): per-wave 128x64 / acc[8][4] variants SPILL (WRITE_SIZE
// 24.6 -> 123 MB, qkv +35 us). Retired; do not retry.
__device__ __forceinline__ void gemm_core256x128(const char* Agc, const char* Bgc,
                                                 char* lds, f32x4 (&acc)[4][4]) {
  constexpr int ABYTES = 16384;     // A tile bytes (256 x 32 bf16)
  constexpr int BUFB = 24576;       // + B tile (128 x 32 bf16)
  constexpr int NT = HID / 32;      // 64 K-tiles

  const int tid = threadIdx.x;
  const int w = tid >> 6, lane = tid & 63;
  const int l16 = lane & 15, quad = lane >> 4;
  const int wr = w >> 1, wc = w & 1;
  const int wb = w * 1024;          // wave-uniform LDS staging base

  const int cu = (tid & 7) ^ ((tid >> 3) & 7);
  const int srcR0 = 2 * (tid >> 3) + (cu >> 2);   // 0..127
  const int srcC = (cu & 3) * 16;
  const char* gA = Agc + (size_t)srcR0 * (HID * 2) + srcC;
  const char* gB = Bgc + (size_t)srcR0 * (HID * 2) + srcC;

  const int acg16 = ((((l16 & 1) << 2) | quad) ^ ((l16 >> 1) & 7)) * 16;
  const int aoff = (wr * 32 + (l16 >> 1)) * 128 + acg16;
  const int boff = ABYTES + (wc * 32 + (l16 >> 1)) * 128 + acg16;

#pragma unroll
  for (int t0 = 0; t0 < 2; ++t0) {
    char* lb = lds + t0 * BUFB;
    load_lds16(gA + t0 * 64, lb + wb);
    load_lds16(gA + (size_t)128 * (HID * 2) + t0 * 64, lb + 8192 + wb);
    load_lds16(gB + t0 * 64, lb + ABYTES + wb);
  }

  char* cur = lds;
  char* stg = lds + 2 * BUFB;
  for (int kt = 0; kt < NT; ++kt) {
    SYNC_VM(3);
    const int ks = (kt + 2 < NT) ? (kt + 2) * 64 : (NT - 1) * 64;

    load_lds16(gA + ks, stg + wb);
    load_lds16(gA + (size_t)128 * (HID * 2) + ks, stg + 8192 + wb);
    load_lds16(gB + ks, stg + ABYTES + wb);
    FENCE();

    bf16x8 af[4], bfr[4];
#pragma unroll
    for (int ni = 0; ni < 4; ++ni)
      bfr[ni] = *(const bf16x8*)(cur + boff + ni * 1024);
#pragma unroll
    for (int mi = 0; mi < 4; ++mi)
      af[mi] = *(const bf16x8*)(cur + aoff + mi * 1024);
    __builtin_amdgcn_s_setprio(1);
#pragma unroll
    for (int mi = 0; mi < 4; ++mi)
#pragma unroll
      for (int ni = 0; ni < 4; ++ni)
        acc[mi][ni] = MFMA16(af[mi], bfr[ni], acc[mi][ni]);
    __builtin_amdgcn_s_setprio(0);

    cur = (cur == lds + 2 * BUFB) ? lds : cur + BUFB;
    stg = (stg == lds + 2 * BUFB) ? lds : stg + BUFB;
  }
  asm volatile("s_waitcnt vmcnt(0)" ::: "memory");
}

// ---------------- BK=64 single-phase core (verified R6/R8/R10; gemm_out only) ----------------
__device__ __forceinline__ void gemm_core_k64(const char* Agc, const char* Bgc,
                                              char* lds, f32x4 (&acc)[4][4]) {
  constexpr int ABYTES = 32768;   // A tile: 256 rows x 64 cols bf16
  constexpr int BUFB = 49152;     // + B tile: 128 rows x 64 cols bf16
  constexpr int NT = HID / 64;    // 32 K-steps

  const int tid = threadIdx.x;
  const int w = tid >> 6, lane = tid & 63;
  const int l16 = lane & 15, quad = lane >> 4;
  const int wr = w >> 1, wc = w & 1;
  const int wb = w * 1024;        // wave-uniform LDS staging base

  const int cu = (lane & 7) ^ ((lane >> 3) & 7);
  const char* gA = Agc + (size_t)(w * 8 + (lane >> 3)) * 4096 + cu * 16;
  const char* gB = Bgc + (size_t)(w * 8 + (lane >> 3)) * 4096 + cu * 16;

  const int aswz = l16 & 7;
  const int a_k0 = ((0 + quad) ^ aswz) * 16;   // ks = 0
  const int a_k1 = ((4 + quad) ^ aswz) * 16;   // ks = 1
  const int arow = (wr * 64 + l16) * 128;
  const int brow = (wc * 64 + l16) * 128;

#pragma unroll
  for (int t0 = 0; t0 < 2; ++t0) {
    char* lb = lds + t0 * BUFB;
#pragma unroll
    for (int j = 0; j < 4; ++j)
      load_lds16(gA + (size_t)j * (64 * 4096) + t0 * 128, lb + wb + j * 8192);
#pragma unroll
    for (int j = 0; j < 2; ++j)
      load_lds16(gB + (size_t)j * (64 * 4096) + t0 * 128, lb + ABYTES + wb + j * 8192);
  }

  char* cur = lds;
  char* stg = lds + 2 * BUFB;
  for (int kt = 0; kt < NT; ++kt) {
    SYNC_VM(6);
    const int ks = (kt + 2 < NT) ? (kt + 2) : (NT - 1);
    const size_t ko = (size_t)ks * 128;

#pragma unroll
    for (int j = 0; j < 4; ++j)
      load_lds16(gA + (size_t)j * (64 * 4096) + ko, stg + wb + j * 8192);
#pragma unroll
    for (int j = 0; j < 2; ++j)
      load_lds16(gB + (size_t)j * (64 * 4096) + ko, stg + ABYTES + wb + j * 8192);
    FENCE();

    const char* Ac = cur;
    const char* Bc = cur + ABYTES;
    bf16x8 af0[4], af1[4], bf0[4], bf1[4];
#pragma unroll
    for (int ni = 0; ni < 4; ++ni) {
      bf0[ni] = *(const bf16x8*)(Bc + brow + ni * 2048 + a_k0);
      bf1[ni] = *(const bf16x8*)(Bc + brow + ni * 2048 + a_k1);
    }
#pragma unroll
    for (int mi = 0; mi < 4; ++mi) {
      af0[mi] = *(const bf16x8*)(Ac + arow + mi * 2048 + a_k0);
      af1[mi] = *(const bf16x8*)(Ac + arow + mi * 2048 + a_k1);
    }
    __builtin_amdgcn_s_setprio(1);
#pragma unroll
    for (int mi = 0; mi < 4; ++mi)
#pragma unroll
      for (int ni = 0; ni < 4; ++ni) {
        acc[mi][ni] = MFMA16(af0[mi], bf0[ni], acc[mi][ni]);
        acc[mi][ni] = MFMA16(af1[mi], bf1[ni], acc[mi][ni]);
      }
    __builtin_amdgcn_s_setprio(0);

    cur = (cur == lds + 2 * BUFB) ? lds : cur + BUFB;
    stg = (stg == lds + 2 * BUFB) ? lds : stg + BUFB;
  }
  asm volatile("s_waitcnt vmcnt(0)" ::: "memory");
}

// ---------------- fused QKV projection + RoPE epilogue (verified R5/R7/R10) ----------------
#define QSCALE 0.1803368801f
#define L2B 0.4152410118f  // log2(10000)/32
__global__ __launch_bounds__(512, 4) void gemm_qkv(const bf16* __restrict__ A,
                                                   const bf16* __restrict__ Wq,
                                                   const bf16* __restrict__ Wk,
                                                   const bf16* __restrict__ Wv,
                                                   bf16* __restrict__ Qb,
                                                   bf16* __restrict__ Kb,
                                                   bf16* __restrict__ Vt) {
  __shared__ __align__(16) char lds[3 * 24576];  // 72 KB -> 2 WG/CU (16 waves)
  const int tileM = blockIdx.x * 256;
  const int n0 = blockIdx.y * 128;
  const bf16* Wp;
  int mode;
  if (n0 < HID) { Wp = Wq + (size_t)n0 * HID; mode = 0; }
  else if (n0 < HID + 512) { Wp = Wk + (size_t)(n0 - HID) * HID; mode = 1; }
  else { Wp = Wv + (size_t)(n0 - HID - 512) * HID; mode = 2; }

  f32x4 acc[4][4];
#pragma unroll
  for (int i = 0; i < 4; ++i)
#pragma unroll
    for (int j = 0; j < 4; ++j) acc[i][j] = (f32x4){0.f, 0.f, 0.f, 0.f};

  gemm_core256x128((const char*)(A + (size_t)tileM * HID), (const char*)Wp, lds, acc);

  const int tid = threadIdx.x;
  const int w = tid >> 6, lane = tid & 63;
  const int l16 = lane & 15, quad = lane >> 4;
  const int wr = w >> 1, wc = w & 1;
  const int mbase = tileM + wr * 64;
  const int cb = n0 + wc * 64;  // 64-aligned -> wave col span = one head

  if (mode == 2) {
    // V: transposed layout [b,kvh,d,s]
#pragma unroll
    for (int mi = 0; mi < 4; ++mi)
#pragma unroll
      for (int ni = 0; ni < 4; ++ni)
#pragma unroll
        for (int r = 0; r < 4; ++r) {
          int grow = mbase + mi * 16 + quad * 4 + r;
          int b = grow >> 11, spos = grow & (SS - 1);
          int nv = cb + ni * 16 + l16 - (HID + 512);
          Vt[(((size_t)(b * NKV + (nv >> 6))) * HD + (nv & 63)) * SS + spos] =
              (bf16)acc[mi][ni][r];
        }
  } else {
    // Q or K: RoPE in fp32 regs; pairs (ni=0,ni=2) at freq l16, (1,3) at l16+16.
    const float inv0 = __builtin_amdgcn_exp2f(-(float)l16 * L2B);
    const float inv1 = __builtin_amdgcn_exp2f(-(float)(l16 + 16) * L2B);
#pragma unroll
    for (int mi = 0; mi < 4; ++mi) {
#pragma unroll
      for (int r = 0; r < 4; ++r) {
        int grow = mbase + mi * 16 + quad * 4 + r;
        int b = grow >> 11, spos = grow & (SS - 1);
        float sn0, cs0, sn1, cs1;
        sincosf((float)spos * inv0, &sn0, &cs0);
        sincosf((float)spos * inv1, &sn1, &cs1);
        float a0 = acc[mi][0][r], a1 = acc[mi][1][r];
        float a2 = acc[mi][2][r], a3 = acc[mi][3][r];
        float o0 = a0 * cs0 - a2 * sn0;
        float o2 = a2 * cs0 + a0 * sn0;
        float o1 = a1 * cs1 - a3 * sn1;
        float o3 = a3 * cs1 + a1 * sn1;
        if (mode == 0) {
          bf16* qp = Qb + (size_t)grow * HID + cb + l16;
          qp[0]  = (bf16)(o0 * QSCALE);
          qp[16] = (bf16)(o1 * QSCALE);
          qp[32] = (bf16)(o2 * QSCALE);
          qp[48] = (bf16)(o3 * QSCALE);
        } else {
          int kvh = (cb - HID) >> 6;
          bf16* kp = Kb + ((size_t)(b * NKV + kvh) * SS + spos) * HD + l16;
          kp[0]  = (bf16)o0;
          kp[16] = (bf16)o1;
          kp[32] = (bf16)o2;
          kp[48] = (bf16)o3;
        }
      }
    }
  }
}

// ---------------- output projection (verified R8/R10: BK=64 single-phase, 256 blocks) ----------------
__global__ __launch_bounds__(512, 2) void gemm_out(const bf16* __restrict__ A,
                                                   const bf16* __restrict__ Wo,
                                                   float* __restrict__ out) {
  __shared__ __align__(16) char lds[3 * 49152];  // 144 KB -> 1 WG/CU
  const int tileM = blockIdx.x * 256;
  const int n0 = blockIdx.y * 128;
  f32x4 acc[4][4];
#pragma unroll
  for (int i = 0; i < 4; ++i)
#pragma unroll
    for (int j = 0; j < 4; ++j) acc[i][j] = (f32x4){0.f, 0.f, 0.f, 0.f};

  gemm_core_k64((const char*)(A + (size_t)tileM * HID),
                (const char*)(Wo + (size_t)n0 * HID), lds, acc);

  const int tid = threadIdx.x;
  const int w = tid >> 6, lane = tid & 63;
  const int l16 = lane & 15, quad = lane >> 4;
  const int wr = w >> 1, wc = w & 1;
#pragma unroll
  for (int mi = 0; mi < 4; ++mi)
#pragma unroll
    for (int ni = 0; ni < 4; ++ni)
#pragma unroll
      for (int r = 0; r < 4; ++r) {
        int grow = tileM + wr * 64 + mi * 16 + quad * 4 + r;
        int gcol = n0 + wc * 64 + ni * 16 + l16;
        out[(size_t)grow * HID + gcol] = acc[mi][ni][r];
      }
}

// ---------------- flash attention v6 (R10 form, no setprio) + masked-subtile skip ----------------
// R12 A/B: setprio in this barrier-locked 4-wave structure cost ~2-4 us
// (m190-regime, not m191) -- removed. New: on the last K/V tile subtile A's
// P is all-zero; skip its P-write, Pbuf reads, and 8 PV MFMAs (identity:
// oA += V*0). skipA is block-uniform -> no divergence.
#define PSTR 72
__global__ __launch_bounds__(256, 3) void attn(const bf16* __restrict__ Qb,
                                               const bf16* __restrict__ Kb,
                                               const bf16* __restrict__ Vt,
                                               bf16* __restrict__ Ctx) {
  __shared__ bf16 Ktile[2][64 * 64];
  __shared__ bf16 Vtile[2][64 * 64];
  __shared__ bf16 Pbuf[4][32 * PSTR];   // per wave: rows 0-15 = A, 16-31 = B
  const int tid = threadIdx.x;
  const int w = tid >> 6, lane = tid & 63;
  const int l16 = lane & 15, quad = lane >> 4;
  const int bh = blockIdx.y, b = bh >> 5, h = bh & 31, kvh = h >> 2;
  bf16* Pw = &Pbuf[w][0];
  const char* Kslice = (const char*)(Kb + ((size_t)(b * NKV + kvh)) * SS * HD);
  const char* Vslice = (const char*)(Vt + ((size_t)(b * NKV + kvh)) * HD * SS);
  const int qrel = w * 16 + l16;        // 0..63 within each 64-row subtile

  const int srow = (lane >> 3) & 7;
  const int pchunk = ((lane & 7) ^ srow) << 4;
  const int so = ((quad ^ (l16 & 7)) << 4);
  const int so2 = so ^ 64;

  const int xA = (int)blockIdx.x;       // 0..7

  int cur = 0;
  {
#pragma unroll
    for (int i = 0; i < 2; ++i) {
      const int r = w * 16 + i * 8 + srow;
      load_lds16(Kslice + (size_t)r * 128 + pchunk,
                 (char*)Ktile[0] + (w * 16 + i * 8) * 128);
      load_lds16(Vslice + (size_t)r * 4096 + pchunk,
                 (char*)Vtile[0] + (w * 16 + i * 8) * 128);
    }
  }

  for (int t = 0; t < 2; ++t) {
    const int X = t ? (15 - xA) : xA;   // 128-row superblock index
    const int qA = X * 128 + qrel;
    const int ktmax = 2 * X + 1;        // last kv tile (64 keys each)

    const bf16* QpA = Qb + ((size_t)(b * SS + qA)) * HID + h * HD + quad * 8;
    bf16x8 qa0 = *(const bf16x8*)QpA;
    bf16x8 qa1 = *(const bf16x8*)(QpA + 32);
    const bf16* QpB = QpA + (size_t)64 * HID;
    bf16x8 qbB0 = *(const bf16x8*)QpB;
    bf16x8 qbB1 = *(const bf16x8*)(QpB + 32);

    float lA = 0.f, lB = 0.f;
    f32x4 oA[4], oB[4];
#pragma unroll
    for (int d = 0; d < 4; ++d) {
      oA[d] = (f32x4){0.f, 0.f, 0.f, 0.f};
      oB[d] = (f32x4){0.f, 0.f, 0.f, 0.f};
    }

    for (int kt = 0; kt <= ktmax; ++kt) {
      __syncthreads();   // cur tile ready (staged a full compute phase ago)

      const bool have_next = (kt < ktmax) || (t == 0);
      if (have_next) {
        const int nkb = (kt < ktmax) ? (kt + 1) * 64 : 0;  // last: tile 0 for pass 1
        const int nb = cur ^ 1;
#pragma unroll
        for (int i = 0; i < 2; ++i) {
          const int r = w * 16 + i * 8 + srow;
          load_lds16(Kslice + (size_t)(nkb + r) * 128 + pchunk,
                     (char*)Ktile[nb] + (w * 16 + i * 8) * 128);
          load_lds16(Vslice + (size_t)r * 4096 + (size_t)nkb * 2 + pchunk,
                     (char*)Vtile[nb] + (w * 16 + i * 8) * 128);
        }
      }

      const char* Kc = (const char*)Ktile[cur] + l16 * 128;
      const char* Vc = (const char*)Vtile[cur] + l16 * 128;
      const bool skipA = (kt == ktmax);       // A fully masked on last tile
      const bool diagA = (kt == ktmax - 1);   // kt == 2X
      const bool diagB = (kt == ktmax);       // kt == 2X+1

#pragma unroll
      for (int nt = 0; nt < 4; ++nt) {
        bf16x8 kf0 = *(const bf16x8*)(Kc + nt * 2048 + so);
        bf16x8 kf1 = *(const bf16x8*)(Kc + nt * 2048 + so2);
        const int krel = nt * 16 + quad * 4;

        if (!skipA) {
          f32x4 s = {0.f, 0.f, 0.f, 0.f};
          s = MFMA16(kf0, qa0, s);   // S^T: row = key, col = q (l16)
          s = MFMA16(kf1, qa1, s);
          bf16x4 pkA;
          if (diagA) {
#pragma unroll
            for (int r = 0; r < 4; ++r) {
              float p = (krel + r > qrel) ? 0.f : __builtin_amdgcn_exp2f(s[r]);
              lA += p;
              pkA[r] = (bf16)p;
            }
          } else {
#pragma unroll
            for (int r = 0; r < 4; ++r) {
              float p = __builtin_amdgcn_exp2f(s[r]);
              lA += p;
              pkA[r] = (bf16)p;
            }
          }
          *(bf16x4*)&Pw[l16 * PSTR + krel] = pkA;
        }

        f32x4 sB = {0.f, 0.f, 0.f, 0.f};
        sB = MFMA16(kf0, qbB0, sB);
        sB = MFMA16(kf1, qbB1, sB);
        bf16x4 pkB;
        if (diagB) {
#pragma unroll
          for (int r = 0; r < 4; ++r) {
            float p = (krel + r > qrel) ? 0.f : __builtin_amdgcn_exp2f(sB[r]);
            lB += p;
            pkB[r] = (bf16)p;
          }
        } else {
#pragma unroll
          for (int r = 0; r < 4; ++r) {
            float p = __builtin_amdgcn_exp2f(sB[r]);
            lB += p;
            pkB[r] = (bf16)p;
          }
        }
        *(bf16x4*)&Pw[(16 + l16) * PSTR + krel] = pkB;
      }

      bf16x8 pA0{}, pA1{};
      if (!skipA) {
        pA0 = *(const bf16x8*)&Pw[l16 * PSTR + quad * 8];
        pA1 = *(const bf16x8*)&Pw[l16 * PSTR + 32 + quad * 8];
      }
      bf16x8 pB0 = *(const bf16x8*)&Pw[(16 + l16) * PSTR + quad * 8];
      bf16x8 pB1 = *(const bf16x8*)&Pw[(16 + l16) * PSTR + 32 + quad * 8];
#pragma unroll
      for (int dn = 0; dn < 4; ++dn) {
        bf16x8 v0 = *(const bf16x8*)(Vc + dn * 2048 + so);
        bf16x8 v1 = *(const bf16x8*)(Vc + dn * 2048 + so2);
        if (!skipA) {
          oA[dn] = MFMA16(v0, pA0, oA[dn]);  // O^T: row = d, col = q
          oA[dn] = MFMA16(v1, pA1, oA[dn]);
        }
        oB[dn] = MFMA16(v0, pB0, oB[dn]);
        oB[dn] = MFMA16(v1, pB1, oB[dn]);
      }
      cur ^= 1;
    }

    lA += __shfl_xor(lA, 16);
    lA += __shfl_xor(lA, 32);
    lB += __shfl_xor(lB, 16);
    lB += __shfl_xor(lB, 32);
    const float invA = 1.0f / lA;
    const float invB = 1.0f / lB;
    bf16* CpA = Ctx + ((size_t)(b * SS + qA)) * HID + h * HD + quad * 4;
    bf16* CpB = CpA + (size_t)64 * HID;
#pragma unroll
    for (int dn = 0; dn < 4; ++dn) {
      bf16x4 ovA, ovB;
#pragma unroll
      for (int r = 0; r < 4; ++r) {
        ovA[r] = (bf16)(oA[dn][r] * invA);
        ovB[r] = (bf16)(oB[dn][r] * invB);
      }
      *(bf16x4*)(CpA + dn * 16) = ovA;
      *(bf16x4*)(CpB + dn * 16) = ovB;
    }
  }
}

// ---------------- launch ----------------
extern "C" void kernel_launch(void* const* d_in, const int* in_sizes, int n_in,
                              void* d_out, int out_size, void* d_ws, size_t ws_size,
                              hipStream_t stream) {
  const float* hs = (const float*)d_in[0];
  const float* Wq = (const float*)d_in[2];
  const float* Wk = (const float*)d_in[3];
  const float* Wv = (const float*)d_in[4];
  const float* Wo = (const float*)d_in[5];

  char* ws = (char*)d_ws;
  bf16* A_b  = (bf16*)(ws);              // 16 MB ; reused as Ctx after QKV gemm
  bf16* Wq_b = (bf16*)(ws + 16777216);   // 8 MB
  bf16* Wk_b = (bf16*)(ws + 25165824);   // 2 MB
  bf16* Wv_b = (bf16*)(ws + 27262976);   // 2 MB
  bf16* Wo_b = (bf16*)(ws + 29360128);   // 8 MB
  bf16* Qb   = (bf16*)(ws + 37748736);   // 16 MB
  bf16* Kb   = (bf16*)(ws + 54525952);   // 4 MB
  bf16* Vt   = (bf16*)(ws + 58720256);   // 4 MB  (end: 62914560)
  bf16* Ctx  = A_b;

  cvt_all<<<18432, 256, 0, stream>>>(hs, Wq, Wk, Wv, Wo, A_b, Wq_b, Wk_b, Wv_b, Wo_b);
  gemm_qkv<<<dim3(MTOT / 256, 24), 512, 0, stream>>>(A_b, Wq_b, Wk_b, Wv_b, Qb, Kb, Vt);
  attn<<<dim3(8, BB * NH), 256, 0, stream>>>(Qb, Kb, Vt, Ctx);
  gemm_out<<<dim3(MTOT / 256, HID / 128), 512, 0, stream>>>(Ctx, Wo_b, (float*)d_out);
}

// Round 14
// 293.912 us; speedup vs baseline: 1.0742x; 1.0003x over previous
//
#include <hip/hip_runtime.h>
#include <math.h>

#define HID 2048
#define NH 32
#define NKV 8
#define HD 64
#define BB 2
#define SS 2048
#define MTOT (BB * SS) // 4096

typedef __bf16 bf16;
typedef __bf16 bf16x8 __attribute__((ext_vector_type(8)));
typedef __bf16 bf16x4 __attribute__((ext_vector_type(4)));
typedef float f32x4 __attribute__((ext_vector_type(4)));

#define MFMA16(a, b, c) __builtin_amdgcn_mfma_f32_16x16x32_bf16((a), (b), (c), 0, 0, 0)

__device__ __forceinline__ void load_lds16(const void* g, void* l) {
  __builtin_amdgcn_global_load_lds((const __attribute__((address_space(1))) void*)g,
                                   (__attribute__((address_space(3))) void*)l, 16, 0, 0);
}

#define FENCE() asm volatile("" ::: "memory")
// Tile-top sync: counted vmcnt (never 0 in main loop) + lgkmcnt(0) so this
// wave's ds_reads have COMPLETED before it enters the barrier (orders them
// against other waves' post-barrier global_load_lds writebacks), then barrier.
#define SYNC_VM(N) do { FENCE(); \
  asm volatile("s_waitcnt vmcnt(" #N ") lgkmcnt(0)" ::: "memory"); \
  __builtin_amdgcn_s_barrier(); FENCE(); } while (0)

// ---------------- fused fp32 -> bf16 convert (EXACT R0 version - fastest measured) ----------------
// R8/R9/R10 A/B: all cvt variants within ~3 us; this one is the best. Leave alone.
__global__ void cvt_all(const float* __restrict__ hs, const float* __restrict__ Wq,
                        const float* __restrict__ Wk, const float* __restrict__ Wv,
                        const float* __restrict__ Wo,
                        bf16* __restrict__ A_b, bf16* __restrict__ Wq_b,
                        bf16* __restrict__ Wk_b, bf16* __restrict__ Wv_b,
                        bf16* __restrict__ Wo_b) {
  int bid = blockIdx.x;
  const float* src;
  bf16* dst;
  if (bid < 8192)       { src = hs; dst = A_b; }
  else if (bid < 12288) { src = Wq; dst = Wq_b; bid -= 8192; }
  else if (bid < 13312) { src = Wk; dst = Wk_b; bid -= 12288; }
  else if (bid < 14336) { src = Wv; dst = Wv_b; bid -= 13312; }
  else                  { src = Wo; dst = Wo_b; bid -= 14336; }
  int i = (bid * 256 + threadIdx.x) * 4;
  float4 v = *(const float4*)(src + i);
  bf16x4 o;
  o[0] = (bf16)v.x; o[1] = (bf16)v.y; o[2] = (bf16)v.z; o[3] = (bf16)v.w;
  *(bf16x4*)(dst + i) = o;
}

// ---------------- BK=32 pipelined core (verified R4/R5/R10): 256x128, 8 waves ----------------
// 72 KB -> 2 WG/CU (16 waves). acc[4][4]=64 regs: no spill (VGPR 56).
// NOTE (R1, R11): per-wave 128x64 / acc[8][4] variants SPILL (WRITE_SIZE
// 24.6 -> 123 MB, qkv +35 us). Retired; do not retry.
__device__ __forceinline__ void gemm_core256x128(const char* Agc, const char* Bgc,
                                                 char* lds, f32x4 (&acc)[4][4]) {
  constexpr int ABYTES = 16384;     // A tile bytes (256 x 32 bf16)
  constexpr int BUFB = 24576;       // + B tile (128 x 32 bf16)
  constexpr int NT = HID / 32;      // 64 K-tiles

  const int tid = threadIdx.x;
  const int w = tid >> 6, lane = tid & 63;
  const int l16 = lane & 15, quad = lane >> 4;
  const int wr = w >> 1, wc = w & 1;
  const int wb = w * 1024;          // wave-uniform LDS staging base

  const int cu = (tid & 7) ^ ((tid >> 3) & 7);
  const int srcR0 = 2 * (tid >> 3) + (cu >> 2);   // 0..127
  const int srcC = (cu & 3) * 16;
  const char* gA = Agc + (size_t)srcR0 * (HID * 2) + srcC;
  const char* gB = Bgc + (size_t)srcR0 * (HID * 2) + srcC;

  const int acg16 = ((((l16 & 1) << 2) | quad) ^ ((l16 >> 1) & 7)) * 16;
  const int aoff = (wr * 32 + (l16 >> 1)) * 128 + acg16;
  const int boff = ABYTES + (wc * 32 + (l16 >> 1)) * 128 + acg16;

#pragma unroll
  for (int t0 = 0; t0 < 2; ++t0) {
    char* lb = lds + t0 * BUFB;
    load_lds16(gA + t0 * 64, lb + wb);
    load_lds16(gA + (size_t)128 * (HID * 2) + t0 * 64, lb + 8192 + wb);
    load_lds16(gB + t0 * 64, lb + ABYTES + wb);
  }

  char* cur = lds;
  char* stg = lds + 2 * BUFB;
  for (int kt = 0; kt < NT; ++kt) {
    SYNC_VM(3);
    const int ks = (kt + 2 < NT) ? (kt + 2) * 64 : (NT - 1) * 64;

    load_lds16(gA + ks, stg + wb);
    load_lds16(gA + (size_t)128 * (HID * 2) + ks, stg + 8192 + wb);
    load_lds16(gB + ks, stg + ABYTES + wb);
    FENCE();

    bf16x8 af[4], bfr[4];
#pragma unroll
    for (int ni = 0; ni < 4; ++ni)
      bfr[ni] = *(const bf16x8*)(cur + boff + ni * 1024);
#pragma unroll
    for (int mi = 0; mi < 4; ++mi)
      af[mi] = *(const bf16x8*)(cur + aoff + mi * 1024);
    __builtin_amdgcn_s_setprio(1);
#pragma unroll
    for (int mi = 0; mi < 4; ++mi)
#pragma unroll
      for (int ni = 0; ni < 4; ++ni)
        acc[mi][ni] = MFMA16(af[mi], bfr[ni], acc[mi][ni]);
    __builtin_amdgcn_s_setprio(0);

    cur = (cur == lds + 2 * BUFB) ? lds : cur + BUFB;
    stg = (stg == lds + 2 * BUFB) ? lds : stg + BUFB;
  }
  asm volatile("s_waitcnt vmcnt(0)" ::: "memory");
}

// ---------------- BK=64 single-phase core (verified R6/R8/R10; gemm_out only) ----------------
// 3 rotating 48 KB buffers (144 KB -> 1 WG/CU), SYNC_VM(6) at step top, one
// barrier per K-step, 32 MFMA/wave/step. (The round-7 2-phase variant
// regressed ~1.7x -- coarse split without fine interleave. Do not re-add.)
__device__ __forceinline__ void gemm_core_k64(const char* Agc, const char* Bgc,
                                              char* lds, f32x4 (&acc)[4][4]) {
  constexpr int ABYTES = 32768;   // A tile: 256 rows x 64 cols bf16
  constexpr int BUFB = 49152;     // + B tile: 128 rows x 64 cols bf16
  constexpr int NT = HID / 64;    // 32 K-steps

  const int tid = threadIdx.x;
  const int w = tid >> 6, lane = tid & 63;
  const int l16 = lane & 15, quad = lane >> 4;
  const int wr = w >> 1, wc = w & 1;
  const int wb = w * 1024;        // wave-uniform LDS staging base

  const int cu = (lane & 7) ^ ((lane >> 3) & 7);
  const char* gA = Agc + (size_t)(w * 8 + (lane >> 3)) * 4096 + cu * 16;
  const char* gB = Bgc + (size_t)(w * 8 + (lane >> 3)) * 4096 + cu * 16;

  const int aswz = l16 & 7;
  const int a_k0 = ((0 + quad) ^ aswz) * 16;   // ks = 0
  const int a_k1 = ((4 + quad) ^ aswz) * 16;   // ks = 1
  const int arow = (wr * 64 + l16) * 128;
  const int brow = (wc * 64 + l16) * 128;

#pragma unroll
  for (int t0 = 0; t0 < 2; ++t0) {
    char* lb = lds + t0 * BUFB;
#pragma unroll
    for (int j = 0; j < 4; ++j)
      load_lds16(gA + (size_t)j * (64 * 4096) + t0 * 128, lb + wb + j * 8192);
#pragma unroll
    for (int j = 0; j < 2; ++j)
      load_lds16(gB + (size_t)j * (64 * 4096) + t0 * 128, lb + ABYTES + wb + j * 8192);
  }

  char* cur = lds;
  char* stg = lds + 2 * BUFB;
  for (int kt = 0; kt < NT; ++kt) {
    SYNC_VM(6);
    const int ks = (kt + 2 < NT) ? (kt + 2) : (NT - 1);
    const size_t ko = (size_t)ks * 128;

#pragma unroll
    for (int j = 0; j < 4; ++j)
      load_lds16(gA + (size_t)j * (64 * 4096) + ko, stg + wb + j * 8192);
#pragma unroll
    for (int j = 0; j < 2; ++j)
      load_lds16(gB + (size_t)j * (64 * 4096) + ko, stg + ABYTES + wb + j * 8192);
    FENCE();

    const char* Ac = cur;
    const char* Bc = cur + ABYTES;
    bf16x8 af0[4], af1[4], bf0[4], bf1[4];
#pragma unroll
    for (int ni = 0; ni < 4; ++ni) {
      bf0[ni] = *(const bf16x8*)(Bc + brow + ni * 2048 + a_k0);
      bf1[ni] = *(const bf16x8*)(Bc + brow + ni * 2048 + a_k1);
    }
#pragma unroll
    for (int mi = 0; mi < 4; ++mi) {
      af0[mi] = *(const bf16x8*)(Ac + arow + mi * 2048 + a_k0);
      af1[mi] = *(const bf16x8*)(Ac + arow + mi * 2048 + a_k1);
    }
    __builtin_amdgcn_s_setprio(1);
#pragma unroll
    for (int mi = 0; mi < 4; ++mi)
#pragma unroll
      for (int ni = 0; ni < 4; ++ni) {
        acc[mi][ni] = MFMA16(af0[mi], bf0[ni], acc[mi][ni]);
        acc[mi][ni] = MFMA16(af1[mi], bf1[ni], acc[mi][ni]);
      }
    __builtin_amdgcn_s_setprio(0);

    cur = (cur == lds + 2 * BUFB) ? lds : cur + BUFB;
    stg = (stg == lds + 2 * BUFB) ? lds : stg + BUFB;
  }
  asm volatile("s_waitcnt vmcnt(0)" ::: "memory");
}

// ---------------- fused QKV projection + RoPE epilogue (verified R5/R7/R10) ----------------
#define QSCALE 0.1803368801f
#define L2B 0.4152410118f  // log2(10000)/32
__global__ __launch_bounds__(512, 4) void gemm_qkv(const bf16* __restrict__ A,
                                                   const bf16* __restrict__ Wq,
                                                   const bf16* __restrict__ Wk,
                                                   const bf16* __restrict__ Wv,
                                                   bf16* __restrict__ Qb,
                                                   bf16* __restrict__ Kb,
                                                   bf16* __restrict__ Vt) {
  __shared__ __align__(16) char lds[3 * 24576];  // 72 KB -> 2 WG/CU (16 waves)
  const int tileM = blockIdx.x * 256;
  const int n0 = blockIdx.y * 128;
  const bf16* Wp;
  int mode;
  if (n0 < HID) { Wp = Wq + (size_t)n0 * HID; mode = 0; }
  else if (n0 < HID + 512) { Wp = Wk + (size_t)(n0 - HID) * HID; mode = 1; }
  else { Wp = Wv + (size_t)(n0 - HID - 512) * HID; mode = 2; }

  f32x4 acc[4][4];
#pragma unroll
  for (int i = 0; i < 4; ++i)
#pragma unroll
    for (int j = 0; j < 4; ++j) acc[i][j] = (f32x4){0.f, 0.f, 0.f, 0.f};

  gemm_core256x128((const char*)(A + (size_t)tileM * HID), (const char*)Wp, lds, acc);

  const int tid = threadIdx.x;
  const int w = tid >> 6, lane = tid & 63;
  const int l16 = lane & 15, quad = lane >> 4;
  const int wr = w >> 1, wc = w & 1;
  const int mbase = tileM + wr * 64;
  const int cb = n0 + wc * 64;  // 64-aligned -> wave col span = one head

  if (mode == 2) {
    // V: transposed layout [b,kvh,d,s]
#pragma unroll
    for (int mi = 0; mi < 4; ++mi)
#pragma unroll
      for (int ni = 0; ni < 4; ++ni)
#pragma unroll
        for (int r = 0; r < 4; ++r) {
          int grow = mbase + mi * 16 + quad * 4 + r;
          int b = grow >> 11, spos = grow & (SS - 1);
          int nv = cb + ni * 16 + l16 - (HID + 512);
          Vt[(((size_t)(b * NKV + (nv >> 6))) * HD + (nv & 63)) * SS + spos] =
              (bf16)acc[mi][ni][r];
        }
  } else {
    // Q or K: RoPE in fp32 regs; pairs (ni=0,ni=2) at freq l16, (1,3) at l16+16.
    const float inv0 = __builtin_amdgcn_exp2f(-(float)l16 * L2B);
    const float inv1 = __builtin_amdgcn_exp2f(-(float)(l16 + 16) * L2B);
#pragma unroll
    for (int mi = 0; mi < 4; ++mi) {
#pragma unroll
      for (int r = 0; r < 4; ++r) {
        int grow = mbase + mi * 16 + quad * 4 + r;
        int b = grow >> 11, spos = grow & (SS - 1);
        float sn0, cs0, sn1, cs1;
        sincosf((float)spos * inv0, &sn0, &cs0);
        sincosf((float)spos * inv1, &sn1, &cs1);
        float a0 = acc[mi][0][r], a1 = acc[mi][1][r];
        float a2 = acc[mi][2][r], a3 = acc[mi][3][r];
        float o0 = a0 * cs0 - a2 * sn0;
        float o2 = a2 * cs0 + a0 * sn0;
        float o1 = a1 * cs1 - a3 * sn1;
        float o3 = a3 * cs1 + a1 * sn1;
        if (mode == 0) {
          bf16* qp = Qb + (size_t)grow * HID + cb + l16;
          qp[0]  = (bf16)(o0 * QSCALE);
          qp[16] = (bf16)(o1 * QSCALE);
          qp[32] = (bf16)(o2 * QSCALE);
          qp[48] = (bf16)(o3 * QSCALE);
        } else {
          int kvh = (cb - HID) >> 6;
          bf16* kp = Kb + ((size_t)(b * NKV + kvh) * SS + spos) * HD + l16;
          kp[0]  = (bf16)o0;
          kp[16] = (bf16)o1;
          kp[32] = (bf16)o2;
          kp[48] = (bf16)o3;
        }
      }
    }
  }
}

// ---------------- output projection (verified R8/R10: BK=64 single-phase, 256 blocks) ----------------
__global__ __launch_bounds__(512, 2) void gemm_out(const bf16* __restrict__ A,
                                                   const bf16* __restrict__ Wo,
                                                   float* __restrict__ out) {
  __shared__ __align__(16) char lds[3 * 49152];  // 144 KB -> 1 WG/CU
  const int tileM = blockIdx.x * 256;
  const int n0 = blockIdx.y * 128;
  f32x4 acc[4][4];
#pragma unroll
  for (int i = 0; i < 4; ++i)
#pragma unroll
    for (int j = 0; j < 4; ++j) acc[i][j] = (f32x4){0.f, 0.f, 0.f, 0.f};

  gemm_core_k64((const char*)(A + (size_t)tileM * HID),
                (const char*)(Wo + (size_t)n0 * HID), lds, acc);

  const int tid = threadIdx.x;
  const int w = tid >> 6, lane = tid & 63;
  const int l16 = lane & 15, quad = lane >> 4;
  const int wr = w >> 1, wc = w & 1;
#pragma unroll
  for (int mi = 0; mi < 4; ++mi)
#pragma unroll
    for (int ni = 0; ni < 4; ++ni)
#pragma unroll
      for (int r = 0; r < 4; ++r) {
        int grow = tileM + wr * 64 + mi * 16 + quad * 4 + r;
        int gcol = n0 + wc * 64 + ni * 16 + l16;
        out[(size_t)grow * HID + gcol] = acc[mi][ni][r];
      }
}

// ---------------- flash attention v6: 128 q-rows per block (verified R5/R10 - best form) ----------------
// R12 A/B: setprio here cost ~2-4 us (barrier-locked waves, m190 regime).
// R13 A/B: masked-subtile tail skip was null-to-negative. Plain form is best.
#define PSTR 72
__global__ __launch_bounds__(256, 3) void attn(const bf16* __restrict__ Qb,
                                               const bf16* __restrict__ Kb,
                                               const bf16* __restrict__ Vt,
                                               bf16* __restrict__ Ctx) {
  __shared__ bf16 Ktile[2][64 * 64];
  __shared__ bf16 Vtile[2][64 * 64];
  __shared__ bf16 Pbuf[4][32 * PSTR];   // per wave: rows 0-15 = A, 16-31 = B
  const int tid = threadIdx.x;
  const int w = tid >> 6, lane = tid & 63;
  const int l16 = lane & 15, quad = lane >> 4;
  const int bh = blockIdx.y, b = bh >> 5, h = bh & 31, kvh = h >> 2;
  bf16* Pw = &Pbuf[w][0];
  const char* Kslice = (const char*)(Kb + ((size_t)(b * NKV + kvh)) * SS * HD);
  const char* Vslice = (const char*)(Vt + ((size_t)(b * NKV + kvh)) * HD * SS);
  const int qrel = w * 16 + l16;        // 0..63 within each 64-row subtile

  const int srow = (lane >> 3) & 7;
  const int pchunk = ((lane & 7) ^ srow) << 4;
  const int so = ((quad ^ (l16 & 7)) << 4);
  const int so2 = so ^ 64;

  const int xA = (int)blockIdx.x;       // 0..7

  int cur = 0;
  {
#pragma unroll
    for (int i = 0; i < 2; ++i) {
      const int r = w * 16 + i * 8 + srow;
      load_lds16(Kslice + (size_t)r * 128 + pchunk,
                 (char*)Ktile[0] + (w * 16 + i * 8) * 128);
      load_lds16(Vslice + (size_t)r * 4096 + pchunk,
                 (char*)Vtile[0] + (w * 16 + i * 8) * 128);
    }
  }

  for (int t = 0; t < 2; ++t) {
    const int X = t ? (15 - xA) : xA;   // 128-row superblock index
    const int qA = X * 128 + qrel;
    const int ktmax = 2 * X + 1;        // last kv tile (64 keys each)

    const bf16* QpA = Qb + ((size_t)(b * SS + qA)) * HID + h * HD + quad * 8;
    bf16x8 qa0 = *(const bf16x8*)QpA;
    bf16x8 qa1 = *(const bf16x8*)(QpA + 32);
    const bf16* QpB = QpA + (size_t)64 * HID;
    bf16x8 qbB0 = *(const bf16x8*)QpB;
    bf16x8 qbB1 = *(const bf16x8*)(QpB + 32);

    float lA = 0.f, lB = 0.f;
    f32x4 oA[4], oB[4];
#pragma unroll
    for (int d = 0; d < 4; ++d) {
      oA[d] = (f32x4){0.f, 0.f, 0.f, 0.f};
      oB[d] = (f32x4){0.f, 0.f, 0.f, 0.f};
    }

    for (int kt = 0; kt <= ktmax; ++kt) {
      __syncthreads();   // cur tile ready (staged a full compute phase ago)

      const bool have_next = (kt < ktmax) || (t == 0);
      if (have_next) {
        const int nkb = (kt < ktmax) ? (kt + 1) * 64 : 0;  // last: tile 0 for pass 1
        const int nb = cur ^ 1;
#pragma unroll
        for (int i = 0; i < 2; ++i) {
          const int r = w * 16 + i * 8 + srow;
          load_lds16(Kslice + (size_t)(nkb + r) * 128 + pchunk,
                     (char*)Ktile[nb] + (w * 16 + i * 8) * 128);
          load_lds16(Vslice + (size_t)r * 4096 + (size_t)nkb * 2 + pchunk,
                     (char*)Vtile[nb] + (w * 16 + i * 8) * 128);
        }
      }

      const char* Kc = (const char*)Ktile[cur] + l16 * 128;
      const char* Vc = (const char*)Vtile[cur] + l16 * 128;
      const bool skipA = (kt == ktmax);       // A fully masked on last tile
      const bool diagA = (kt == ktmax - 1);   // kt == 2X
      const bool diagB = (kt == ktmax);       // kt == 2X+1

#pragma unroll
      for (int nt = 0; nt < 4; ++nt) {
        bf16x8 kf0 = *(const bf16x8*)(Kc + nt * 2048 + so);
        bf16x8 kf1 = *(const bf16x8*)(Kc + nt * 2048 + so2);
        const int krel = nt * 16 + quad * 4;

        bf16x4 pkA;
        if (skipA) {
          pkA[0] = (bf16)0.f; pkA[1] = (bf16)0.f;
          pkA[2] = (bf16)0.f; pkA[3] = (bf16)0.f;
        } else {
          f32x4 s = {0.f, 0.f, 0.f, 0.f};
          s = MFMA16(kf0, qa0, s);   // S^T: row = key, col = q (l16)
          s = MFMA16(kf1, qa1, s);
          if (diagA) {
#pragma unroll
            for (int r = 0; r < 4; ++r) {
              float p = (krel + r > qrel) ? 0.f : __builtin_amdgcn_exp2f(s[r]);
              lA += p;
              pkA[r] = (bf16)p;
            }
          } else {
#pragma unroll
            for (int r = 0; r < 4; ++r) {
              float p = __builtin_amdgcn_exp2f(s[r]);
              lA += p;
              pkA[r] = (bf16)p;
            }
          }
        }
        *(bf16x4*)&Pw[l16 * PSTR + krel] = pkA;

        f32x4 sB = {0.f, 0.f, 0.f, 0.f};
        sB = MFMA16(kf0, qbB0, sB);
        sB = MFMA16(kf1, qbB1, sB);
        bf16x4 pkB;
        if (diagB) {
#pragma unroll
          for (int r = 0; r < 4; ++r) {
            float p = (krel + r > qrel) ? 0.f : __builtin_amdgcn_exp2f(sB[r]);
            lB += p;
            pkB[r] = (bf16)p;
          }
        } else {
#pragma unroll
          for (int r = 0; r < 4; ++r) {
            float p = __builtin_amdgcn_exp2f(sB[r]);
            lB += p;
            pkB[r] = (bf16)p;
          }
        }
        *(bf16x4*)&Pw[(16 + l16) * PSTR + krel] = pkB;
      }

      bf16x8 pA0 = *(const bf16x8*)&Pw[l16 * PSTR + quad * 8];
      bf16x8 pA1 = *(const bf16x8*)&Pw[l16 * PSTR + 32 + quad * 8];
      bf16x8 pB0 = *(const bf16x8*)&Pw[(16 + l16) * PSTR + quad * 8];
      bf16x8 pB1 = *(const bf16x8*)&Pw[(16 + l16) * PSTR + 32 + quad * 8];
#pragma unroll
      for (int dn = 0; dn < 4; ++dn) {
        bf16x8 v0 = *(const bf16x8*)(Vc + dn * 2048 + so);
        bf16x8 v1 = *(const bf16x8*)(Vc + dn * 2048 + so2);
        oA[dn] = MFMA16(v0, pA0, oA[dn]);  // O^T: row = d, col = q
        oA[dn] = MFMA16(v1, pA1, oA[dn]);
        oB[dn] = MFMA16(v0, pB0, oB[dn]);
        oB[dn] = MFMA16(v1, pB1, oB[dn]);
      }
      cur ^= 1;
    }

    lA += __shfl_xor(lA, 16);
    lA += __shfl_xor(lA, 32);
    lB += __shfl_xor(lB, 16);
    lB += __shfl_xor(lB, 32);
    const float invA = 1.0f / lA;
    const float invB = 1.0f / lB;
    bf16* CpA = Ctx + ((size_t)(b * SS + qA)) * HID + h * HD + quad * 4;
    bf16* CpB = CpA + (size_t)64 * HID;
#pragma unroll
    for (int dn = 0; dn < 4; ++dn) {
      bf16x4 ovA, ovB;
#pragma unroll
      for (int r = 0; r < 4; ++r) {
        ovA[r] = (bf16)(oA[dn][r] * invA);
        ovB[r] = (bf16)(oB[dn][r] * invB);
      }
      *(bf16x4*)(CpA + dn * 16) = ovA;
      *(bf16x4*)(CpB + dn * 16) = ovB;
    }
  }
}

// ---------------- launch ----------------
extern "C" void kernel_launch(void* const* d_in, const int* in_sizes, int n_in,
                              void* d_out, int out_size, void* d_ws, size_t ws_size,
                              hipStream_t stream) {
  const float* hs = (const float*)d_in[0];
  const float* Wq = (const float*)d_in[2];
  const float* Wk = (const float*)d_in[3];
  const float* Wv = (const float*)d_in[4];
  const float* Wo = (const float*)d_in[5];

  char* ws = (char*)d_ws;
  bf16* A_b  = (bf16*)(ws);              // 16 MB ; reused as Ctx after QKV gemm
  bf16* Wq_b = (bf16*)(ws + 16777216);   // 8 MB
  bf16* Wk_b = (bf16*)(ws + 25165824);   // 2 MB
  bf16* Wv_b = (bf16*)(ws + 27262976);   // 2 MB
  bf16* Wo_b = (bf16*)(ws + 29360128);   // 8 MB
  bf16* Qb   = (bf16*)(ws + 37748736);   // 16 MB
  bf16* Kb   = (bf16*)(ws + 54525952);   // 4 MB
  bf16* Vt   = (bf16*)(ws + 58720256);   // 4 MB  (end: 62914560)
  bf16* Ctx  = A_b;

  cvt_all<<<18432, 256, 0, stream>>>(hs, Wq, Wk, Wv, Wo, A_b, Wq_b, Wk_b, Wv_b, Wo_b);
  gemm_qkv<<<dim3(MTOT / 256, 24), 512, 0, stream>>>(A_b, Wq_b, Wk_b, Wv_b, Qb, Kb, Vt);
  attn<<<dim3(8, BB * NH), 256, 0, stream>>>(Qb, Kb, Vt, Ctx);
  gemm_out<<<dim3(MTOT / 256, HID / 128), 512, 0, stream>>>(Ctx, Wo_b, (float*)d_out);
}